// Round 1
// baseline (21817.232 us; speedup 1.0000x reference)
//
#include <hip/hip_runtime.h>
#include <math.h>

#define TSTEPS 8
#define FDIM 128
#define HDIM 128
#define ODIM 64
#define GDIM 512   // 4*HDIM gate width

__device__ __forceinline__ float sigmf(float x) { return 1.0f / (1.0f + __expf(-x)); }

// ---------------- small elementwise / setup kernels ----------------

__global__ void transpose_lstm_w(const float* __restrict__ wih, const float* __restrict__ whh,
                                 float* __restrict__ wihT, float* __restrict__ whhT) {
    int idx = blockIdx.x * 256 + threadIdx.x;
    if (idx < GDIM * HDIM) {
        int jj = idx / HDIM;   // gate col 0..511
        int k  = idx % HDIM;   // input dim 0..127
        wihT[k * GDIM + jj] = wih[idx];
        whhT[k * GDIM + jj] = whh[idx];
    }
}

__global__ void zero_hc(float4* __restrict__ h, float4* __restrict__ c, int n4) {
    int idx = blockIdx.x * 256 + threadIdx.x;
    if (idx < n4) {
        float4 z = make_float4(0.f, 0.f, 0.f, 0.f);
        h[idx] = z; c[idx] = z;
    }
}

__global__ void deg_init(float* __restrict__ dinv, int n) {
    int idx = blockIdx.x * 256 + threadIdx.x;
    if (idx < n) dinv[idx] = 1.0f;   // self-loop contribution
}

__global__ void deg_count(const int* __restrict__ dst, float* __restrict__ dinv, int e) {
    int idx = blockIdx.x * 256 + threadIdx.x;
    if (idx < e) atomicAdd(&dinv[dst[idx]], 1.0f);
}

__global__ void deg_fin(float* __restrict__ dinv, int n) {
    int idx = blockIdx.x * 256 + threadIdx.x;
    if (idx < n) dinv[idx] = rsqrtf(dinv[idx]);
}

// agg[v] = xw[v] * dinv[v]^2  (self-loop edge), initializes the accumulator
__global__ void agg_self(const float4* __restrict__ xw, const float* __restrict__ dinv,
                         float4* __restrict__ agg, int n) {
    int idx = blockIdx.x * 256 + threadIdx.x;
    if (idx < n * 32) {
        int r = idx >> 5;
        float di = dinv[r];
        float c = di * di;
        float4 v = xw[idx];
        agg[idx] = make_float4(v.x * c, v.y * c, v.z * c, v.w * c);
    }
}

// one edge handled by 32 threads, 4 floats each
__global__ void agg_edges(const int* __restrict__ src, const int* __restrict__ dst,
                          const float* __restrict__ xw, const float* __restrict__ dinv,
                          float* __restrict__ agg, int e) {
    int tid = blockIdx.x * 256 + threadIdx.x;
    int ed = tid >> 5;
    if (ed < e) {
        int c = tid & 31;
        int s = src[ed], d = dst[ed];
        float coef = dinv[s] * dinv[d];
        float4 v = ((const float4*)xw)[(size_t)s * 32 + c];
        float* o = agg + (size_t)d * FDIM + c * 4;
        atomicAdd(o + 0, v.x * coef);
        atomicAdd(o + 1, v.y * coef);
        atomicAdd(o + 2, v.z * coef);
        atomicAdd(o + 3, v.w * coef);
    }
}

__global__ void bias_relu4(float4* __restrict__ buf, const float4* __restrict__ bias, int n) {
    int idx = blockIdx.x * 256 + threadIdx.x;
    if (idx < n * 32) {
        int j = idx & 31;
        float4 b = bias[j];
        float4 v = buf[idx];
        v.x = fmaxf(v.x + b.x, 0.f);
        v.y = fmaxf(v.y + b.y, 0.f);
        v.z = fmaxf(v.z + b.z, 0.f);
        v.w = fmaxf(v.w + b.w, 0.f);
        buf[idx] = v;
    }
}

__global__ void copy_hc(const float4* __restrict__ h, const float4* __restrict__ c,
                        float4* __restrict__ oh, float4* __restrict__ oc, int n4) {
    int idx = blockIdx.x * 256 + threadIdx.x;
    if (idx < n4) { oh[idx] = h[idx]; oc[idx] = c[idx]; }
}

// ---------------- GEMM: C[N,WN] = A[N,128] @ W[128,WN] (+bias, +relu) ----------------
// W is k-major (row k contiguous in columns) so lane-consecutive j reads coalesce.

template<int WN, int R, bool RELU, bool BIAS>
__global__ __launch_bounds__(WN) void gemm_k128(
    const float* __restrict__ A, const float* __restrict__ W,
    const float* __restrict__ bias, float* __restrict__ C, int nrows)
{
    __shared__ float As[R][FDIM];
    int r0 = blockIdx.x * R;
    int rows_here = nrows - r0; if (rows_here > R) rows_here = R;
    if (rows_here <= 0) return;
    int j = threadIdx.x;

    const float4* A4 = (const float4*)(A + (size_t)r0 * FDIM);
    float4* As4 = (float4*)(&As[0][0]);
    int nv = rows_here * (FDIM / 4);
    for (int v = j; v < nv; v += WN) As4[v] = A4[v];
    __syncthreads();

    float b = 0.f;
    if (BIAS) b = bias[j];
    for (int rc = 0; rc < rows_here; rc += 8) {
        float acc[8];
        #pragma unroll
        for (int r = 0; r < 8; r++) acc[r] = b;
        #pragma unroll 4
        for (int k = 0; k < FDIM; k++) {
            float w = W[k * WN + j];
            #pragma unroll
            for (int r = 0; r < 8; r++) acc[r] = fmaf(As[rc + r][k], w, acc[r]);
        }
        #pragma unroll
        for (int r = 0; r < 8; r++) {
            int row = r0 + rc + r;
            if (row < nrows) {
                float v = acc[r];
                if (RELU) v = fmaxf(v, 0.f);
                C[(size_t)row * WN + j] = v;
            }
        }
    }
}

// ---------------- fused LSTM step: gates + state update for 32 rows / block ----------------

__global__ __launch_bounds__(512) void lstm_step(
    const float* __restrict__ emb, const float* __restrict__ wihT, const float* __restrict__ whhT,
    const float* __restrict__ bih, const float* __restrict__ bhh,
    float* __restrict__ hbuf, float* __restrict__ cbuf, int nrows)
{
    const int R = 32;
    __shared__ float xs[R][FDIM];
    __shared__ float hs[R][FDIM];
    __shared__ float gs[R][GDIM];
    int r0 = blockIdx.x * R;
    int rows_here = nrows - r0; if (rows_here > R) rows_here = R;
    if (rows_here <= 0) return;
    int j = threadIdx.x;   // gate column 0..511

    const float4* e4 = (const float4*)(emb + (size_t)r0 * FDIM);
    const float4* h4 = (const float4*)(hbuf + (size_t)r0 * FDIM);
    float4* xs4 = (float4*)xs;
    float4* hs4 = (float4*)hs;
    int nv = rows_here * (FDIM / 4);
    for (int v = j; v < nv; v += 512) { xs4[v] = e4[v]; hs4[v] = h4[v]; }
    __syncthreads();

    float bsum = bih[j] + bhh[j];
    for (int rc = 0; rc < rows_here; rc += 8) {
        float acc[8];
        #pragma unroll
        for (int r = 0; r < 8; r++) acc[r] = bsum;
        #pragma unroll 4
        for (int k = 0; k < FDIM; k++) {
            float wx = wihT[k * GDIM + j];
            float wh = whhT[k * GDIM + j];
            #pragma unroll
            for (int r = 0; r < 8; r++)
                acc[r] = fmaf(xs[rc + r][k], wx, fmaf(hs[rc + r][k], wh, acc[r]));
        }
        #pragma unroll
        for (int r = 0; r < 8; r++) gs[rc + r][j] = acc[r];
    }
    __syncthreads();

    for (int p = j; p < rows_here * HDIM; p += 512) {
        int r = p >> 7, hh = p & 127;
        float gi = gs[r][hh];
        float gf = gs[r][HDIM + hh];
        float gg = gs[r][2 * HDIM + hh];
        float go = gs[r][3 * HDIM + hh];
        size_t o = (size_t)(r0 + r) * HDIM + hh;
        float c_old = cbuf[o];
        float c_new = sigmf(gf) * c_old + sigmf(gi) * tanhf(gg);
        float h_new = sigmf(go) * tanhf(c_new);
        cbuf[o] = c_new;
        hbuf[o] = h_new;
    }
}

// ---------------- launch ----------------

static inline int cdiv(long long a, long long b) { return (int)((a + b - 1) / b); }

extern "C" void kernel_launch(void* const* d_in, const int* in_sizes, int n_in,
                              void* d_out, int out_size, void* d_ws, size_t ws_size,
                              hipStream_t stream) {
    const float* x_seq = (const float*)d_in[0];
    const int*   edges = (const int*)d_in[1];
    const float* W1    = (const float*)d_in[2];
    const float* b1    = (const float*)d_in[3];
    const float* W2    = (const float*)d_in[4];
    const float* b2    = (const float*)d_in[5];
    const float* Wih   = (const float*)d_in[6];
    const float* Whh   = (const float*)d_in[7];
    const float* bih   = (const float*)d_in[8];
    const float* bhh   = (const float*)d_in[9];
    const float* Wout  = (const float*)d_in[10];
    const float* bout  = (const float*)d_in[11];
    float* out = (float*)d_out;

    const int N = in_sizes[0] / (TSTEPS * FDIM);   // 50000
    const int E = in_sizes[1] / (2 * TSTEPS);      // 600000

    // workspace layout (floats)
    float* ws = (float*)d_ws;
    size_t nPad = ((size_t)N + 255) & ~(size_t)255;
    size_t nf = (size_t)N * FDIM;
    float* dinv = ws;
    float* xw   = ws + nPad;
    float* h1   = xw + nf;
    float* emb  = h1 + nf;
    float* hbuf = emb + nf;
    float* cbuf = hbuf + nf;
    float* wihT = cbuf + nf;
    float* whhT = wihT + (size_t)FDIM * GDIM;

    const int n4 = N * 32;   // float4 count of an [N,128] buffer

    transpose_lstm_w<<<cdiv(GDIM * HDIM, 256), 256, 0, stream>>>(Wih, Whh, wihT, whhT);
    zero_hc<<<cdiv(n4, 256), 256, 0, stream>>>((float4*)hbuf, (float4*)cbuf, n4);

    const int GEMM_R = 64;
    for (int t = 0; t < TSTEPS; t++) {
        const int* srcp = edges + (size_t)t * 2 * E;
        const int* dstp = srcp + E;
        const float* xt = x_seq + (size_t)t * nf;

        deg_init<<<cdiv(N, 256), 256, 0, stream>>>(dinv, N);
        deg_count<<<cdiv(E, 256), 256, 0, stream>>>(dstp, dinv, E);
        deg_fin<<<cdiv(N, 256), 256, 0, stream>>>(dinv, N);

        // layer 1
        gemm_k128<FDIM, GEMM_R, false, false><<<cdiv(N, GEMM_R), FDIM, 0, stream>>>(xt, W1, nullptr, xw, N);
        agg_self<<<cdiv(n4, 256), 256, 0, stream>>>((const float4*)xw, dinv, (float4*)h1, N);
        agg_edges<<<cdiv((long long)E * 32, 256), 256, 0, stream>>>(srcp, dstp, xw, dinv, h1, E);
        bias_relu4<<<cdiv(n4, 256), 256, 0, stream>>>((float4*)h1, (const float4*)b1, N);

        // layer 2
        gemm_k128<FDIM, GEMM_R, false, false><<<cdiv(N, GEMM_R), FDIM, 0, stream>>>(h1, W2, nullptr, xw, N);
        agg_self<<<cdiv(n4, 256), 256, 0, stream>>>((const float4*)xw, dinv, (float4*)emb, N);
        agg_edges<<<cdiv((long long)E * 32, 256), 256, 0, stream>>>(srcp, dstp, xw, dinv, emb, E);
        bias_relu4<<<cdiv(n4, 256), 256, 0, stream>>>((float4*)emb, (const float4*)b2, N);

        // LSTM step
        lstm_step<<<cdiv(N, 32), 512, 0, stream>>>(emb, wihT, whhT, bih, bhh, hbuf, cbuf, N);
    }

    // head: out[0:N*64] = hT @ Wout + bout
    gemm_k128<ODIM, 64, false, true><<<cdiv(N, 64), ODIM, 0, stream>>>(hbuf, Wout, bout, out, N);
    // copy hT, cT
    float* out_h = out + (size_t)N * ODIM;
    float* out_c = out_h + nf;
    copy_hc<<<cdiv(n4, 256), 256, 0, stream>>>((const float4*)hbuf, (const float4*)cbuf,
                                               (float4*)out_h, (float4*)out_c, n4);
}

// Round 2
// 6520.817 us; speedup vs baseline: 3.3458x; 3.3458x over previous
//
#include <hip/hip_runtime.h>
#include <math.h>

#define TSTEPS 8
#define FDIM 128
#define HDIM 128
#define ODIM 64
#define GDIM 512   // 4*HDIM gate width
#define SCAN_CHUNK 1024

__device__ __forceinline__ float sigmf(float x) { return 1.0f / (1.0f + __expf(-x)); }

// ---------------- small setup kernels ----------------

__global__ void transpose_lstm_w(const float* __restrict__ wih, const float* __restrict__ whh,
                                 float* __restrict__ wihT, float* __restrict__ whhT) {
    int idx = blockIdx.x * 256 + threadIdx.x;
    if (idx < GDIM * HDIM) {
        int jj = idx / HDIM;   // gate col 0..511
        int k  = idx % HDIM;   // input dim 0..127
        wihT[k * GDIM + jj] = wih[idx];
        whhT[k * GDIM + jj] = whh[idx];
    }
}

__global__ void zero_hc(float4* __restrict__ h, float4* __restrict__ c, int n4) {
    int idx = blockIdx.x * 256 + threadIdx.x;
    if (idx < n4) {
        float4 z = make_float4(0.f, 0.f, 0.f, 0.f);
        h[idx] = z; c[idx] = z;
    }
}

__global__ void zero_int(int* __restrict__ p, int n) {
    int idx = blockIdx.x * 256 + threadIdx.x;
    if (idx < n) p[idx] = 0;
}

__global__ void deg_count(const int* __restrict__ dst, int* __restrict__ deg, int e) {
    int idx = blockIdx.x * 256 + threadIdx.x;
    if (idx < e) atomicAdd(&deg[dst[idx]], 1);
}

__global__ void deg_to_dinv(const int* __restrict__ deg, float* __restrict__ dinv, int n) {
    int idx = blockIdx.x * 256 + threadIdx.x;
    if (idx < n) dinv[idx] = rsqrtf((float)(deg[idx] + 1));   // +1 self-loop
}

// ---------------- prefix scan (exclusive) over deg[N] -> row_start[N+1] ----------------

__global__ __launch_bounds__(256) void scan_partial(const int* __restrict__ deg,
                                                    int* __restrict__ partial, int n) {
    __shared__ int s[256];
    int b = blockIdx.x, t = threadIdx.x;
    int base = b * SCAN_CHUNK + t * 4;
    int sum = 0;
    #pragma unroll
    for (int i = 0; i < 4; i++) { int idx = base + i; if (idx < n) sum += deg[idx]; }
    s[t] = sum; __syncthreads();
    for (int off = 128; off > 0; off >>= 1) {
        if (t < off) s[t] += s[t + off];
        __syncthreads();
    }
    if (t == 0) partial[b] = s[0];
}

__global__ void scan_offsets(int* __restrict__ partial, int* __restrict__ row_start,
                             int nchunks, int n) {
    if (threadIdx.x == 0 && blockIdx.x == 0) {
        int run = 0;
        for (int i = 0; i < nchunks; i++) { int v = partial[i]; partial[i] = run; run += v; }
        row_start[n] = run;
    }
}

__global__ __launch_bounds__(256) void scan_final(const int* __restrict__ deg,
                                                  const int* __restrict__ partial,
                                                  int* __restrict__ row_start,
                                                  int* __restrict__ cursor, int n) {
    __shared__ int s[256];
    int b = blockIdx.x, t = threadIdx.x;
    int base = b * SCAN_CHUNK + t * 4;
    int v[4]; int local = 0;
    #pragma unroll
    for (int i = 0; i < 4; i++) { int idx = base + i; v[i] = (idx < n) ? deg[idx] : 0; local += v[i]; }
    s[t] = local; __syncthreads();
    // Hillis-Steele inclusive scan
    for (int off = 1; off < 256; off <<= 1) {
        int add = (t >= off) ? s[t - off] : 0;
        __syncthreads();
        s[t] += add;
        __syncthreads();
    }
    int excl = s[t] - local + partial[b];
    #pragma unroll
    for (int i = 0; i < 4; i++) {
        int idx = base + i;
        if (idx < n) { row_start[idx] = excl; cursor[idx] = excl; }
        excl += v[i];
    }
}

__global__ void edge_scatter(const int* __restrict__ src, const int* __restrict__ dst,
                             int* __restrict__ cursor, int* __restrict__ csr_src, int e) {
    int idx = blockIdx.x * 256 + threadIdx.x;
    if (idx < e) {
        int pos = atomicAdd(&cursor[dst[idx]], 1);
        csr_src[pos] = src[idx];
    }
}

// ---------------- gather aggregation: one wave per dst row ----------------
// out[d] = relu( bias + dinv[d]^2 * xw[d] + sum_{s in N(d)} dinv[s]*dinv[d]*xw[s] )

__global__ __launch_bounds__(256) void agg_gather(
    const int* __restrict__ row_start, const int* __restrict__ csr_src,
    const float* __restrict__ xw, const float* __restrict__ dinv,
    const float* __restrict__ bias, float* __restrict__ outb, int n)
{
    int w = (blockIdx.x * 256 + threadIdx.x) >> 6;
    int lane = threadIdx.x & 63;
    if (w >= n) return;
    const float2* x2 = (const float2*)xw;
    float dr = dinv[w];
    float2 v = x2[(size_t)w * 64 + lane];
    float cc = dr * dr;
    float a0 = v.x * cc, a1 = v.y * cc;
    int e0 = row_start[w], e1 = row_start[w + 1];
    for (int e = e0; e < e1; e++) {
        int s = csr_src[e];
        float coef = dinv[s] * dr;
        float2 u = x2[(size_t)s * 64 + lane];
        a0 = fmaf(u.x, coef, a0);
        a1 = fmaf(u.y, coef, a1);
    }
    float2 b = ((const float2*)bias)[lane];
    a0 = fmaxf(a0 + b.x, 0.f);
    a1 = fmaxf(a1 + b.y, 0.f);
    ((float2*)outb)[(size_t)w * 64 + lane] = make_float2(a0, a1);
}

__global__ void copy_hc(const float4* __restrict__ h, const float4* __restrict__ c,
                        float4* __restrict__ oh, float4* __restrict__ oc, int n4) {
    int idx = blockIdx.x * 256 + threadIdx.x;
    if (idx < n4) { oh[idx] = h[idx]; oc[idx] = c[idx]; }
}

// ---------------- GEMM: C[N,WN] = A[N,128] @ W[128,WN] (+bias) ----------------

template<int WN, int R, bool BIAS>
__global__ __launch_bounds__(WN) void gemm_k128(
    const float* __restrict__ A, const float* __restrict__ W,
    const float* __restrict__ bias, float* __restrict__ C, int nrows)
{
    __shared__ float As[R][FDIM];
    int r0 = blockIdx.x * R;
    int rows_here = nrows - r0; if (rows_here > R) rows_here = R;
    if (rows_here <= 0) return;
    int j = threadIdx.x;

    const float4* A4 = (const float4*)(A + (size_t)r0 * FDIM);
    float4* As4 = (float4*)(&As[0][0]);
    int nv = rows_here * (FDIM / 4);
    for (int v = j; v < nv; v += WN) As4[v] = A4[v];
    __syncthreads();

    float b = 0.f;
    if (BIAS) b = bias[j];
    for (int rc = 0; rc < rows_here; rc += 8) {
        float acc[8];
        #pragma unroll
        for (int r = 0; r < 8; r++) acc[r] = b;
        #pragma unroll 4
        for (int k = 0; k < FDIM; k++) {
            float w = W[k * WN + j];
            #pragma unroll
            for (int r = 0; r < 8; r++) acc[r] = fmaf(As[rc + r][k], w, acc[r]);
        }
        #pragma unroll
        for (int r = 0; r < 8; r++) {
            int row = r0 + rc + r;
            if (row < nrows) C[(size_t)row * WN + j] = acc[r];
        }
    }
}

// ---------------- fused LSTM step ----------------

__global__ __launch_bounds__(512) void lstm_step(
    const float* __restrict__ emb, const float* __restrict__ wihT, const float* __restrict__ whhT,
    const float* __restrict__ bih, const float* __restrict__ bhh,
    float* __restrict__ hbuf, float* __restrict__ cbuf, int nrows)
{
    const int R = 32;
    __shared__ float xs[R][FDIM];
    __shared__ float hs[R][FDIM];
    __shared__ float gs[R][GDIM];
    int r0 = blockIdx.x * R;
    int rows_here = nrows - r0; if (rows_here > R) rows_here = R;
    if (rows_here <= 0) return;
    int j = threadIdx.x;   // gate column 0..511

    const float4* e4 = (const float4*)(emb + (size_t)r0 * FDIM);
    const float4* h4 = (const float4*)(hbuf + (size_t)r0 * FDIM);
    float4* xs4 = (float4*)xs;
    float4* hs4 = (float4*)hs;
    int nv = rows_here * (FDIM / 4);
    for (int v = j; v < nv; v += 512) { xs4[v] = e4[v]; hs4[v] = h4[v]; }
    __syncthreads();

    float bsum = bih[j] + bhh[j];
    for (int rc = 0; rc < rows_here; rc += 8) {
        float acc[8];
        #pragma unroll
        for (int r = 0; r < 8; r++) acc[r] = bsum;
        #pragma unroll 4
        for (int k = 0; k < FDIM; k++) {
            float wx = wihT[k * GDIM + j];
            float wh = whhT[k * GDIM + j];
            #pragma unroll
            for (int r = 0; r < 8; r++)
                acc[r] = fmaf(xs[rc + r][k], wx, fmaf(hs[rc + r][k], wh, acc[r]));
        }
        #pragma unroll
        for (int r = 0; r < 8; r++) gs[rc + r][j] = acc[r];
    }
    __syncthreads();

    for (int p = j; p < rows_here * HDIM; p += 512) {
        int r = p >> 7, hh = p & 127;
        float gi = gs[r][hh];
        float gf = gs[r][HDIM + hh];
        float gg = gs[r][2 * HDIM + hh];
        float go = gs[r][3 * HDIM + hh];
        size_t o = (size_t)(r0 + r) * HDIM + hh;
        float c_old = cbuf[o];
        float c_new = sigmf(gf) * c_old + sigmf(gi) * tanhf(gg);
        float h_new = sigmf(go) * tanhf(c_new);
        cbuf[o] = c_new;
        hbuf[o] = h_new;
    }
}

// ---------------- launch ----------------

static inline int cdiv(long long a, long long b) { return (int)((a + b - 1) / b); }

extern "C" void kernel_launch(void* const* d_in, const int* in_sizes, int n_in,
                              void* d_out, int out_size, void* d_ws, size_t ws_size,
                              hipStream_t stream) {
    const float* x_seq = (const float*)d_in[0];
    const int*   edges = (const int*)d_in[1];
    const float* W1    = (const float*)d_in[2];
    const float* b1    = (const float*)d_in[3];
    const float* W2    = (const float*)d_in[4];
    const float* b2    = (const float*)d_in[5];
    const float* Wih   = (const float*)d_in[6];
    const float* Whh   = (const float*)d_in[7];
    const float* bih   = (const float*)d_in[8];
    const float* bhh   = (const float*)d_in[9];
    const float* Wout  = (const float*)d_in[10];
    const float* bout  = (const float*)d_in[11];
    float* out = (float*)d_out;

    const int N = in_sizes[0] / (TSTEPS * FDIM);   // 50000
    const int E = in_sizes[1] / (2 * TSTEPS);      // 600000
    const int NCHUNKS = cdiv(N, SCAN_CHUNK);

    // workspace layout (floats then ints)
    float* ws = (float*)d_ws;
    size_t nPad = ((size_t)N + 255) & ~(size_t)255;
    size_t nf = (size_t)N * FDIM;
    float* dinv = ws;
    float* xw   = ws + nPad;
    float* h1   = xw + nf;
    float* emb  = h1 + nf;
    float* hbuf = emb + nf;
    float* cbuf = hbuf + nf;
    float* wihT = cbuf + nf;
    float* whhT = wihT + (size_t)FDIM * GDIM;
    int* iws      = (int*)(whhT + (size_t)FDIM * GDIM);
    int* deg      = iws;
    int* row_start= deg + nPad;
    int* cursor   = row_start + nPad;
    int* partial  = cursor + nPad;
    int* csr_src  = partial + 256;

    const int n4 = N * 32;   // float4 count of an [N,128] buffer

    transpose_lstm_w<<<cdiv(GDIM * HDIM, 256), 256, 0, stream>>>(Wih, Whh, wihT, whhT);
    zero_hc<<<cdiv(n4, 256), 256, 0, stream>>>((float4*)hbuf, (float4*)cbuf, n4);

    const int GEMM_R = 64;
    for (int t = 0; t < TSTEPS; t++) {
        const int* srcp = edges + (size_t)t * 2 * E;
        const int* dstp = srcp + E;
        const float* xt = x_seq + (size_t)t * nf;

        // ---- CSR build for this timestep ----
        zero_int<<<cdiv(N, 256), 256, 0, stream>>>(deg, N);
        deg_count<<<cdiv(E, 256), 256, 0, stream>>>(dstp, deg, E);
        scan_partial<<<NCHUNKS, 256, 0, stream>>>(deg, partial, N);
        scan_offsets<<<1, 64, 0, stream>>>(partial, row_start, NCHUNKS, N);
        scan_final<<<NCHUNKS, 256, 0, stream>>>(deg, partial, row_start, cursor, N);
        deg_to_dinv<<<cdiv(N, 256), 256, 0, stream>>>(deg, dinv, N);
        edge_scatter<<<cdiv(E, 256), 256, 0, stream>>>(srcp, dstp, cursor, csr_src, E);

        // ---- layer 1 ----
        gemm_k128<FDIM, GEMM_R, false><<<cdiv(N, GEMM_R), FDIM, 0, stream>>>(xt, W1, nullptr, xw, N);
        agg_gather<<<cdiv((long long)N * 64, 256), 256, 0, stream>>>(row_start, csr_src, xw, dinv, b1, h1, N);

        // ---- layer 2 ----
        gemm_k128<FDIM, GEMM_R, false><<<cdiv(N, GEMM_R), FDIM, 0, stream>>>(h1, W2, nullptr, xw, N);
        agg_gather<<<cdiv((long long)N * 64, 256), 256, 0, stream>>>(row_start, csr_src, xw, dinv, b2, emb, N);

        // ---- LSTM step ----
        lstm_step<<<cdiv(N, 32), 512, 0, stream>>>(emb, wihT, whhT, bih, bhh, hbuf, cbuf, N);
    }

    // head: out[0:N*64] = hT @ Wout + bout
    gemm_k128<ODIM, 64, true><<<cdiv(N, 64), ODIM, 0, stream>>>(hbuf, Wout, bout, out, N);
    // copy hT, cT
    float* out_h = out + (size_t)N * ODIM;
    float* out_c = out_h + nf;
    copy_hc<<<cdiv(n4, 256), 256, 0, stream>>>((const float4*)hbuf, (const float4*)cbuf,
                                               (float4*)out_h, (float4*)out_c, n4);
}

// Round 3
// 4007.449 us; speedup vs baseline: 5.4442x; 1.6272x over previous
//
#include <hip/hip_runtime.h>
#include <math.h>

#define TSTEPS 8
#define FDIM 128
#define HDIM 128
#define ODIM 64
#define GDIM 512   // 4*HDIM gate width
#define SCAN_CHUNK 1024

__device__ __forceinline__ float sigmf(float x) { return 1.0f / (1.0f + __expf(-x)); }

// ---------------- small setup kernels ----------------

// wcat[k][col]: k in [0,256) = concat(emb-dim, h-dim); bsum[col] = bih+bhh
__global__ void prep_lstm_w(const float* __restrict__ wih, const float* __restrict__ whh,
                            const float* __restrict__ bih, const float* __restrict__ bhh,
                            float* __restrict__ wcat, float* __restrict__ bsum) {
    int idx = blockIdx.x * 256 + threadIdx.x;
    if (idx < 256 * GDIM) {
        int k = idx >> 9;        // 0..255
        int col = idx & 511;     // 0..511
        float v = (k < HDIM) ? wih[col * HDIM + k] : whh[col * HDIM + (k - HDIM)];
        wcat[idx] = v;
        if (k == 0) bsum[col] = bih[col] + bhh[col];
    }
}

__global__ void zero_hc(float4* __restrict__ h, float4* __restrict__ c, int n4) {
    int idx = blockIdx.x * 256 + threadIdx.x;
    if (idx < n4) {
        float4 z = make_float4(0.f, 0.f, 0.f, 0.f);
        h[idx] = z; c[idx] = z;
    }
}

__global__ void zero_int(int* __restrict__ p, int n) {
    int idx = blockIdx.x * 256 + threadIdx.x;
    if (idx < n) p[idx] = 0;
}

__global__ void deg_count(const int* __restrict__ dst, int* __restrict__ deg, int e) {
    int idx = blockIdx.x * 256 + threadIdx.x;
    if (idx < e) atomicAdd(&deg[dst[idx]], 1);
}

__global__ void deg_to_dinv(const int* __restrict__ deg, float* __restrict__ dinv, int n) {
    int idx = blockIdx.x * 256 + threadIdx.x;
    if (idx < n) dinv[idx] = rsqrtf((float)(deg[idx] + 1));   // +1 self-loop
}

// ---------------- prefix scan (exclusive) over deg[N] -> row_start[N+1] ----------------

__global__ __launch_bounds__(256) void scan_partial(const int* __restrict__ deg,
                                                    int* __restrict__ partial, int n) {
    __shared__ int s[256];
    int b = blockIdx.x, t = threadIdx.x;
    int base = b * SCAN_CHUNK + t * 4;
    int sum = 0;
    #pragma unroll
    for (int i = 0; i < 4; i++) { int idx = base + i; if (idx < n) sum += deg[idx]; }
    s[t] = sum; __syncthreads();
    for (int off = 128; off > 0; off >>= 1) {
        if (t < off) s[t] += s[t + off];
        __syncthreads();
    }
    if (t == 0) partial[b] = s[0];
}

__global__ void scan_offsets(int* __restrict__ partial, int* __restrict__ row_start,
                             int nchunks, int n) {
    if (threadIdx.x == 0 && blockIdx.x == 0) {
        int run = 0;
        for (int i = 0; i < nchunks; i++) { int v = partial[i]; partial[i] = run; run += v; }
        row_start[n] = run;
    }
}

__global__ __launch_bounds__(256) void scan_final(const int* __restrict__ deg,
                                                  const int* __restrict__ partial,
                                                  int* __restrict__ row_start,
                                                  int* __restrict__ cursor, int n) {
    __shared__ int s[256];
    int b = blockIdx.x, t = threadIdx.x;
    int base = b * SCAN_CHUNK + t * 4;
    int v[4]; int local = 0;
    #pragma unroll
    for (int i = 0; i < 4; i++) { int idx = base + i; v[i] = (idx < n) ? deg[idx] : 0; local += v[i]; }
    s[t] = local; __syncthreads();
    for (int off = 1; off < 256; off <<= 1) {
        int add = (t >= off) ? s[t - off] : 0;
        __syncthreads();
        s[t] += add;
        __syncthreads();
    }
    int excl = s[t] - local + partial[b];
    #pragma unroll
    for (int i = 0; i < 4; i++) {
        int idx = base + i;
        if (idx < n) { row_start[idx] = excl; cursor[idx] = excl; }
        excl += v[i];
    }
}

__global__ void edge_scatter(const int* __restrict__ src, const int* __restrict__ dst,
                             int* __restrict__ cursor, int* __restrict__ csr_src, int e) {
    int idx = blockIdx.x * 256 + threadIdx.x;
    if (idx < e) {
        int pos = atomicAdd(&cursor[dst[idx]], 1);
        csr_src[pos] = src[idx];
    }
}

// ---------------- gather aggregation: one wave per dst row ----------------

__global__ __launch_bounds__(256) void agg_gather(
    const int* __restrict__ row_start, const int* __restrict__ csr_src,
    const float* __restrict__ xw, const float* __restrict__ dinv,
    const float* __restrict__ bias, float* __restrict__ outb, int n)
{
    int w = (blockIdx.x * 256 + threadIdx.x) >> 6;
    int lane = threadIdx.x & 63;
    if (w >= n) return;
    const float2* x2 = (const float2*)xw;
    float dr = dinv[w];
    float2 v = x2[(size_t)w * 64 + lane];
    float cc = dr * dr;
    float a0 = v.x * cc, a1 = v.y * cc;
    int e0 = row_start[w], e1 = row_start[w + 1];
    for (int e = e0; e < e1; e++) {
        int s = csr_src[e];
        float coef = dinv[s] * dr;
        float2 u = x2[(size_t)s * 64 + lane];
        a0 = fmaf(u.x, coef, a0);
        a1 = fmaf(u.y, coef, a1);
    }
    float2 b = ((const float2*)bias)[lane];
    a0 = fmaxf(a0 + b.x, 0.f);
    a1 = fmaxf(a1 + b.y, 0.f);
    ((float2*)outb)[(size_t)w * 64 + lane] = make_float2(a0, a1);
}

__global__ void copy_hc(const float4* __restrict__ h, const float4* __restrict__ c,
                        float4* __restrict__ oh, float4* __restrict__ oc, int n4) {
    int idx = blockIdx.x * 256 + threadIdx.x;
    if (idx < n4) { oh[idx] = h[idx]; oc[idx] = c[idx]; }
}

// ---------------- GCN GEMM: C[N,128] = A[N,128] @ W[128,128] ----------------
// Block: 64 rows x 128 cols, 256 threads, thread tile 8 rows x 4 cols.
// Wave-uniform LDS broadcast reads; coalesced W loads (W is k-major).

__global__ __launch_bounds__(256) void gemm_gcn(
    const float* __restrict__ A, const float* __restrict__ W,
    float* __restrict__ C, int nrows)
{
    __shared__ float As[64][FDIM];
    int r0 = blockIdx.x * 64;
    int rows_here = nrows - r0; if (rows_here > 64) rows_here = 64;
    if (rows_here <= 0) return;
    int tid = threadIdx.x;
    int cg = tid & 31;        // col group 0..31
    int tr = tid >> 5;        // row group 0..7 (8 rows each)

    const float4* A4 = (const float4*)(A + (size_t)r0 * FDIM);
    float4* As4 = (float4*)As;
    for (int v = tid; v < 64 * 32; v += 256) {
        int row = v >> 5;
        float4 val = make_float4(0.f, 0.f, 0.f, 0.f);
        if (row < rows_here) val = A4[v];
        As4[v] = val;
    }
    __syncthreads();

    float acc[8][4];
    #pragma unroll
    for (int r = 0; r < 8; r++)
        #pragma unroll
        for (int c = 0; c < 4; c++) acc[r][c] = 0.f;

    for (int k = 0; k < FDIM; k += 4) {
        float bv[4][4];
        #pragma unroll
        for (int kk = 0; kk < 4; kk++)
            #pragma unroll
            for (int c = 0; c < 4; c++)
                bv[kk][c] = W[(k + kk) * FDIM + cg + c * 32];
        #pragma unroll
        for (int r = 0; r < 8; r++) {
            float4 a = *(const float4*)&As[tr * 8 + r][k];
            #pragma unroll
            for (int c = 0; c < 4; c++) {
                acc[r][c] = fmaf(a.x, bv[0][c], acc[r][c]);
                acc[r][c] = fmaf(a.y, bv[1][c], acc[r][c]);
                acc[r][c] = fmaf(a.z, bv[2][c], acc[r][c]);
                acc[r][c] = fmaf(a.w, bv[3][c], acc[r][c]);
            }
        }
    }

    #pragma unroll
    for (int r = 0; r < 8; r++) {
        int row = r0 + tr * 8 + r;
        if (row < nrows) {
            #pragma unroll
            for (int c = 0; c < 4; c++)
                C[(size_t)row * FDIM + cg + c * 32] = acc[r][c];
        }
    }
}

// ---------------- fused LSTM step: gates GEMM + state update, all in registers ----------------
// gates[N,512] = [emb | h] @ wcat[256,512] + bsum; block = 32 rows x 512 cols,
// 256 threads, thread tile 8 rows x 8 cols (cols cg + c*64). Each thread holds
// all 4 gates for h-columns cg and cg+64 -> elementwise update in registers.

__global__ __launch_bounds__(256) void lstm_fused(
    const float* __restrict__ emb, const float* __restrict__ wcat,
    const float* __restrict__ bsum,
    float* __restrict__ hbuf, float* __restrict__ cbuf, int nrows)
{
    __shared__ float As[32][256];
    int r0 = blockIdx.x * 32;
    int rows_here = nrows - r0; if (rows_here > 32) rows_here = 32;
    if (rows_here <= 0) return;
    int tid = threadIdx.x;
    int cg = tid & 63;        // 0..63
    int tr = tid >> 6;        // row group 0..3 (8 rows each); wave-uniform

    const float4* e4 = (const float4*)(emb + (size_t)r0 * FDIM);
    const float4* h4 = (const float4*)(hbuf + (size_t)r0 * FDIM);
    float4* As4 = (float4*)As;
    for (int v = tid; v < 32 * 64; v += 256) {
        int row = v >> 6, q = v & 63;
        float4 val = make_float4(0.f, 0.f, 0.f, 0.f);
        if (row < rows_here)
            val = (q < 32) ? e4[row * 32 + q] : h4[row * 32 + (q - 32)];
        As4[v] = val;
    }
    __syncthreads();

    float acc[8][8];
    #pragma unroll
    for (int c = 0; c < 8; c++) {
        float b = bsum[cg + c * 64];
        #pragma unroll
        for (int r = 0; r < 8; r++) acc[r][c] = b;
    }

    for (int k = 0; k < 256; k += 4) {
        float bv[4][8];
        #pragma unroll
        for (int kk = 0; kk < 4; kk++)
            #pragma unroll
            for (int c = 0; c < 8; c++)
                bv[kk][c] = wcat[(k + kk) * GDIM + cg + c * 64];
        #pragma unroll
        for (int r = 0; r < 8; r++) {
            float4 a = *(const float4*)&As[tr * 8 + r][k];
            #pragma unroll
            for (int c = 0; c < 8; c++) {
                acc[r][c] = fmaf(a.x, bv[0][c], acc[r][c]);
                acc[r][c] = fmaf(a.y, bv[1][c], acc[r][c]);
                acc[r][c] = fmaf(a.z, bv[2][c], acc[r][c]);
                acc[r][c] = fmaf(a.w, bv[3][c], acc[r][c]);
            }
        }
    }

    // elementwise update: cols cg (c = 0,2,4,6) and cg+64 (c = 1,3,5,7)
    #pragma unroll
    for (int r = 0; r < 8; r++) {
        int row = r0 + tr * 8 + r;
        if (row < nrows) {
            size_t base = (size_t)row * HDIM;
            {
                float gi = acc[r][0], gf = acc[r][2], gg = acc[r][4], go = acc[r][6];
                float c_old = cbuf[base + cg];
                float c_new = sigmf(gf) * c_old + sigmf(gi) * tanhf(gg);
                cbuf[base + cg] = c_new;
                hbuf[base + cg] = sigmf(go) * tanhf(c_new);
            }
            {
                float gi = acc[r][1], gf = acc[r][3], gg = acc[r][5], go = acc[r][7];
                float c_old = cbuf[base + 64 + cg];
                float c_new = sigmf(gf) * c_old + sigmf(gi) * tanhf(gg);
                cbuf[base + 64 + cg] = c_new;
                hbuf[base + 64 + cg] = sigmf(go) * tanhf(c_new);
            }
        }
    }
}

// ---------------- head GEMM: out[N,64] = h @ Wout + bout ----------------

template<int WN, int R, bool BIAS>
__global__ __launch_bounds__(WN) void gemm_k128(
    const float* __restrict__ A, const float* __restrict__ W,
    const float* __restrict__ bias, float* __restrict__ C, int nrows)
{
    __shared__ float As[R][FDIM];
    int r0 = blockIdx.x * R;
    int rows_here = nrows - r0; if (rows_here > R) rows_here = R;
    if (rows_here <= 0) return;
    int j = threadIdx.x;

    const float4* A4 = (const float4*)(A + (size_t)r0 * FDIM);
    float4* As4 = (float4*)(&As[0][0]);
    int nv = rows_here * (FDIM / 4);
    for (int v = j; v < nv; v += WN) As4[v] = A4[v];
    __syncthreads();

    float b = 0.f;
    if (BIAS) b = bias[j];
    for (int rc = 0; rc < rows_here; rc += 8) {
        float acc[8];
        #pragma unroll
        for (int r = 0; r < 8; r++) acc[r] = b;
        #pragma unroll 4
        for (int k = 0; k < FDIM; k++) {
            float w = W[k * WN + j];
            #pragma unroll
            for (int r = 0; r < 8; r++) acc[r] = fmaf(As[rc + r][k], w, acc[r]);
        }
        #pragma unroll
        for (int r = 0; r < 8; r++) {
            int row = r0 + rc + r;
            if (row < nrows) C[(size_t)row * WN + j] = acc[r];
        }
    }
}

// ---------------- launch ----------------

static inline int cdiv(long long a, long long b) { return (int)((a + b - 1) / b); }

extern "C" void kernel_launch(void* const* d_in, const int* in_sizes, int n_in,
                              void* d_out, int out_size, void* d_ws, size_t ws_size,
                              hipStream_t stream) {
    const float* x_seq = (const float*)d_in[0];
    const int*   edges = (const int*)d_in[1];
    const float* W1    = (const float*)d_in[2];
    const float* b1    = (const float*)d_in[3];
    const float* W2    = (const float*)d_in[4];
    const float* b2    = (const float*)d_in[5];
    const float* Wih   = (const float*)d_in[6];
    const float* Whh   = (const float*)d_in[7];
    const float* bih   = (const float*)d_in[8];
    const float* bhh   = (const float*)d_in[9];
    const float* Wout  = (const float*)d_in[10];
    const float* bout  = (const float*)d_in[11];
    float* out = (float*)d_out;

    const int N = in_sizes[0] / (TSTEPS * FDIM);   // 50000
    const int E = in_sizes[1] / (2 * TSTEPS);      // 600000
    const int NCHUNKS = cdiv(N, SCAN_CHUNK);

    // workspace layout (floats then ints)
    float* ws = (float*)d_ws;
    size_t nPad = ((size_t)N + 255) & ~(size_t)255;
    size_t nf = (size_t)N * FDIM;
    float* dinv = ws;
    float* xw   = ws + nPad;
    float* h1   = xw + nf;
    float* emb  = h1 + nf;
    float* hbuf = emb + nf;
    float* cbuf = hbuf + nf;
    float* wcat = cbuf + nf;                        // [256][512]
    float* bsum = wcat + (size_t)256 * GDIM;        // [512]
    int* iws      = (int*)(bsum + GDIM);
    int* deg      = iws;
    int* row_start= deg + nPad;
    int* cursor   = row_start + nPad;
    int* partial  = cursor + nPad;
    int* csr_src  = partial + 256;

    const int n4 = N * 32;   // float4 count of an [N,128] buffer

    prep_lstm_w<<<cdiv(256 * GDIM, 256), 256, 0, stream>>>(Wih, Whh, bih, bhh, wcat, bsum);
    zero_hc<<<cdiv(n4, 256), 256, 0, stream>>>((float4*)hbuf, (float4*)cbuf, n4);

    for (int t = 0; t < TSTEPS; t++) {
        const int* srcp = edges + (size_t)t * 2 * E;
        const int* dstp = srcp + E;
        const float* xt = x_seq + (size_t)t * nf;

        // ---- CSR build for this timestep ----
        zero_int<<<cdiv(N, 256), 256, 0, stream>>>(deg, N);
        deg_count<<<cdiv(E, 256), 256, 0, stream>>>(dstp, deg, E);
        scan_partial<<<NCHUNKS, 256, 0, stream>>>(deg, partial, N);
        scan_offsets<<<1, 64, 0, stream>>>(partial, row_start, NCHUNKS, N);
        scan_final<<<NCHUNKS, 256, 0, stream>>>(deg, partial, row_start, cursor, N);
        deg_to_dinv<<<cdiv(N, 256), 256, 0, stream>>>(deg, dinv, N);
        edge_scatter<<<cdiv(E, 256), 256, 0, stream>>>(srcp, dstp, cursor, csr_src, E);

        // ---- layer 1 ----
        gemm_gcn<<<cdiv(N, 64), 256, 0, stream>>>(xt, W1, xw, N);
        agg_gather<<<cdiv((long long)N * 64, 256), 256, 0, stream>>>(row_start, csr_src, xw, dinv, b1, h1, N);

        // ---- layer 2 ----
        gemm_gcn<<<cdiv(N, 64), 256, 0, stream>>>(h1, W2, xw, N);
        agg_gather<<<cdiv((long long)N * 64, 256), 256, 0, stream>>>(row_start, csr_src, xw, dinv, b2, emb, N);

        // ---- LSTM step (fused GEMM + elementwise) ----
        lstm_fused<<<cdiv(N, 32), 256, 0, stream>>>(emb, wcat, bsum, hbuf, cbuf, N);
    }

    // head: out[0:N*64] = hT @ Wout + bout
    gemm_k128<ODIM, 64, true><<<cdiv(N, 64), ODIM, 0, stream>>>(hbuf, Wout, bout, out, N);
    // copy hT, cT
    float* out_h = out + (size_t)N * ODIM;
    float* out_c = out_h + nf;
    copy_hc<<<cdiv(n4, 256), 256, 0, stream>>>((const float4*)hbuf, (const float4*)cbuf,
                                               (float4*)out_h, (float4*)out_c, n4);
}

// Round 4
// 2726.272 us; speedup vs baseline: 8.0026x; 1.4699x over previous
//
#include <hip/hip_runtime.h>
#include <math.h>

#define TSTEPS 8
#define FDIM 128
#define HDIM 128
#define ODIM 64
#define GDIM 512
#define SCAN_CHUNK 1024

typedef __attribute__((ext_vector_type(4))) float f32x4;
typedef __attribute__((ext_vector_type(8))) short s8;

__device__ __forceinline__ float sigmf(float x) { return 1.0f / (1.0f + __expf(-x)); }

__device__ __forceinline__ ushort f2bf(float x) {
    uint u = __float_as_uint(x);
    u += 0x7FFFu + ((u >> 16) & 1u);
    return (ushort)(u >> 16);
}
__device__ __forceinline__ float bf2f(ushort h) { return __uint_as_float(((uint)h) << 16); }

// ---------------- small setup kernels ----------------

// wcat[k][col]: k in [0,256) = concat(emb-dim, h-dim); bsum[col] = bih+bhh
__global__ void prep_lstm_w(const float* __restrict__ wih, const float* __restrict__ whh,
                            const float* __restrict__ bih, const float* __restrict__ bhh,
                            float* __restrict__ wcat, float* __restrict__ bsum) {
    int idx = blockIdx.x * 256 + threadIdx.x;
    if (idx < 256 * GDIM) {
        int k = idx >> 9;
        int col = idx & 511;
        float v = (k < HDIM) ? wih[col * HDIM + k] : whh[col * HDIM + (k - HDIM)];
        wcat[idx] = v;
        if (k == 0) bsum[col] = bih[col] + bhh[col];
    }
}

// pack B [K][NC] f32 (k-major) into MFMA-frag order, split hi/lo bf16.
// frag map: lane l, elem j -> k = kt*32 + (l>>4)*8 + j, col = nt*16 + (l&15)
__global__ void pack_b(const float* __restrict__ B, int K, int NC,
                       uint* __restrict__ hi, uint* __restrict__ lo) {
    int total = (K / 32) * (NC / 16) * 256;
    int idx = blockIdx.x * 256 + threadIdx.x;
    if (idx >= total) return;
    int d = idx & 3, l = (idx >> 2) & 63, t = idx >> 8;
    int NT = NC / 16;
    int kt = t / NT, nt = t % NT;
    int k = kt * 32 + (l >> 4) * 8 + d * 2;
    int col = nt * 16 + (l & 15);
    float va = B[(size_t)k * NC + col];
    float vb = B[(size_t)(k + 1) * NC + col];
    ushort ha = f2bf(va), hb = f2bf(vb);
    float ra = va - bf2f(ha), rb = vb - bf2f(hb);
    hi[idx] = (uint)ha | ((uint)hb << 16);
    lo[idx] = (uint)f2bf(ra) | ((uint)f2bf(rb) << 16);
}

__global__ void zero4(float4* __restrict__ p, int n4) {
    int idx = blockIdx.x * 256 + threadIdx.x;
    if (idx < n4) p[idx] = make_float4(0.f, 0.f, 0.f, 0.f);
}

__global__ void zero_int(int* __restrict__ p, int n) {
    int idx = blockIdx.x * 256 + threadIdx.x;
    if (idx < n) p[idx] = 0;
}

__global__ void deg_count(const int* __restrict__ dst, int* __restrict__ deg, int e) {
    int idx = blockIdx.x * 256 + threadIdx.x;
    if (idx < e) atomicAdd(&deg[dst[idx]], 1);
}

__global__ void deg_to_dinv(const int* __restrict__ deg, float* __restrict__ dinv, int n) {
    int idx = blockIdx.x * 256 + threadIdx.x;
    if (idx < n) dinv[idx] = rsqrtf((float)(deg[idx] + 1));
}

// ---------------- prefix scan ----------------

__global__ __launch_bounds__(256) void scan_partial(const int* __restrict__ deg,
                                                    int* __restrict__ partial, int n) {
    __shared__ int s[256];
    int b = blockIdx.x, t = threadIdx.x;
    int base = b * SCAN_CHUNK + t * 4;
    int sum = 0;
    #pragma unroll
    for (int i = 0; i < 4; i++) { int idx = base + i; if (idx < n) sum += deg[idx]; }
    s[t] = sum; __syncthreads();
    for (int off = 128; off > 0; off >>= 1) {
        if (t < off) s[t] += s[t + off];
        __syncthreads();
    }
    if (t == 0) partial[b] = s[0];
}

__global__ void scan_offsets(int* __restrict__ partial, int* __restrict__ row_start,
                             int nchunks, int n) {
    if (threadIdx.x == 0 && blockIdx.x == 0) {
        int run = 0;
        for (int i = 0; i < nchunks; i++) { int v = partial[i]; partial[i] = run; run += v; }
        row_start[n] = run;
    }
}

__global__ __launch_bounds__(256) void scan_final(const int* __restrict__ deg,
                                                  const int* __restrict__ partial,
                                                  int* __restrict__ row_start,
                                                  int* __restrict__ cursor, int n) {
    __shared__ int s[256];
    int b = blockIdx.x, t = threadIdx.x;
    int base = b * SCAN_CHUNK + t * 4;
    int v[4]; int local = 0;
    #pragma unroll
    for (int i = 0; i < 4; i++) { int idx = base + i; v[i] = (idx < n) ? deg[idx] : 0; local += v[i]; }
    s[t] = local; __syncthreads();
    for (int off = 1; off < 256; off <<= 1) {
        int add = (t >= off) ? s[t - off] : 0;
        __syncthreads();
        s[t] += add;
        __syncthreads();
    }
    int excl = s[t] - local + partial[b];
    #pragma unroll
    for (int i = 0; i < 4; i++) {
        int idx = base + i;
        if (idx < n) { row_start[idx] = excl; cursor[idx] = excl; }
        excl += v[i];
    }
}

__global__ void edge_scatter(const int* __restrict__ src, const int* __restrict__ dst,
                             int* __restrict__ cursor, int* __restrict__ csr_src, int e) {
    int idx = blockIdx.x * 256 + threadIdx.x;
    if (idx < e) {
        int pos = atomicAdd(&cursor[dst[idx]], 1);
        csr_src[pos] = src[idx];
    }
}

// ---------------- gather aggregation: one wave per dst row, writes split bf16 ----------------

__global__ __launch_bounds__(256) void agg_gather(
    const int* __restrict__ row_start, const int* __restrict__ csr_src,
    const float* __restrict__ xw, const float* __restrict__ dinv,
    const float* __restrict__ bias, uint* __restrict__ ohi, uint* __restrict__ olo, int n)
{
    int w = (blockIdx.x * 256 + threadIdx.x) >> 6;
    int lane = threadIdx.x & 63;
    if (w >= n) return;
    const float2* x2 = (const float2*)xw;
    float dr = dinv[w];
    float2 v = x2[(size_t)w * 64 + lane];
    float cc = dr * dr;
    float a0 = v.x * cc, a1 = v.y * cc;
    int e0 = row_start[w], e1 = row_start[w + 1];
    for (int e = e0; e < e1; e++) {
        int s = csr_src[e];
        float coef = dinv[s] * dr;
        float2 u = x2[(size_t)s * 64 + lane];
        a0 = fmaf(u.x, coef, a0);
        a1 = fmaf(u.y, coef, a1);
    }
    float2 b = ((const float2*)bias)[lane];
    a0 = fmaxf(a0 + b.x, 0.f);
    a1 = fmaxf(a1 + b.y, 0.f);
    ushort h0 = f2bf(a0), h1 = f2bf(a1);
    ohi[(size_t)w * 64 + lane] = (uint)h0 | ((uint)h1 << 16);
    olo[(size_t)w * 64 + lane] = (uint)f2bf(a0 - bf2f(h0)) | ((uint)f2bf(a1 - bf2f(h1)) << 16);
}

__global__ void copy_hc(const float4* __restrict__ h, const float4* __restrict__ c,
                        float4* __restrict__ oh, float4* __restrict__ oc, int n4) {
    int idx = blockIdx.x * 256 + threadIdx.x;
    if (idx < n4) { oh[idx] = h[idx]; oc[idx] = c[idx]; }
}

// ---------------- MFMA GEMM: C[N,128] = A[N,128] @ W[128,128], split-bf16 ----------------
// block: 64 rows x 128 cols, 4 waves; wave (wm,wn): M-tiles {2wm,2wm+1}, N-tiles {4wn..4wn+3}

template<bool SPLITSRC>
__global__ __launch_bounds__(256) void gemm_mfma128(
    const float* __restrict__ A32, const uint4* __restrict__ Ahi, const uint4* __restrict__ Alo,
    const uint4* __restrict__ Bhi, const uint4* __restrict__ Blo,
    float* __restrict__ C, int nrows)
{
    __shared__ ushort AsH[64][136];
    __shared__ ushort AsL[64][136];
    const int r0 = blockIdx.x * 64;
    const int tid = threadIdx.x;

    if (SPLITSRC) {
        for (int v = tid; v < 64 * 16; v += 256) {
            int row = v >> 4, seg = v & 15;
            uint4 h = make_uint4(0, 0, 0, 0), L = make_uint4(0, 0, 0, 0);
            if (r0 + row < nrows) {
                h = Ahi[(size_t)(r0 + row) * 16 + seg];
                L = Alo[(size_t)(r0 + row) * 16 + seg];
            }
            *(uint4*)&AsH[row][seg * 8] = h;
            *(uint4*)&AsL[row][seg * 8] = L;
        }
    } else {
        for (int v = tid; v < 64 * 16; v += 256) {
            int row = v >> 4, seg = v & 15;
            float4 a = make_float4(0.f, 0.f, 0.f, 0.f), b = a;
            if (r0 + row < nrows) {
                const float4* src = (const float4*)A32 + (size_t)(r0 + row) * 32 + seg * 2;
                a = src[0]; b = src[1];
            }
            float vv[8] = {a.x, a.y, a.z, a.w, b.x, b.y, b.z, b.w};
            uint hh[4], ll[4];
            #pragma unroll
            for (int i = 0; i < 4; i++) {
                float v0 = vv[2 * i], v1 = vv[2 * i + 1];
                ushort h0 = f2bf(v0), h1 = f2bf(v1);
                hh[i] = (uint)h0 | ((uint)h1 << 16);
                ll[i] = (uint)f2bf(v0 - bf2f(h0)) | ((uint)f2bf(v1 - bf2f(h1)) << 16);
            }
            *(uint4*)&AsH[row][seg * 8] = make_uint4(hh[0], hh[1], hh[2], hh[3]);
            *(uint4*)&AsL[row][seg * 8] = make_uint4(ll[0], ll[1], ll[2], ll[3]);
        }
    }
    __syncthreads();

    const int l = tid & 63, w = tid >> 6;
    const int wm = w & 1, wn = w >> 1;
    const int lrow = l & 15, lk = (l >> 4) * 8;

    f32x4 acc[2][4];
    #pragma unroll
    for (int m = 0; m < 2; m++)
        #pragma unroll
        for (int p = 0; p < 4; p++) acc[m][p] = (f32x4){0.f, 0.f, 0.f, 0.f};

    for (int kt = 0; kt < 4; kt++) {
        s8 aH[2], aL[2];
        #pragma unroll
        for (int m = 0; m < 2; m++) {
            int row = (2 * wm + m) * 16 + lrow;
            aH[m] = *(const s8*)&AsH[row][kt * 32 + lk];
            aL[m] = *(const s8*)&AsL[row][kt * 32 + lk];
        }
        #pragma unroll
        for (int p = 0; p < 4; p++) {
            int nt = 4 * wn + p;
            uint4 bh4 = Bhi[(kt * 8 + nt) * 64 + l];
            uint4 bl4 = Blo[(kt * 8 + nt) * 64 + l];
            s8 bh = __builtin_bit_cast(s8, bh4);
            s8 bl = __builtin_bit_cast(s8, bl4);
            #pragma unroll
            for (int m = 0; m < 2; m++) {
                acc[m][p] = __builtin_amdgcn_mfma_f32_16x16x32_bf16(aH[m], bh, acc[m][p], 0, 0, 0);
                acc[m][p] = __builtin_amdgcn_mfma_f32_16x16x32_bf16(aH[m], bl, acc[m][p], 0, 0, 0);
                acc[m][p] = __builtin_amdgcn_mfma_f32_16x16x32_bf16(aL[m], bh, acc[m][p], 0, 0, 0);
            }
        }
    }

    const int lr4 = (l >> 4) * 4;
    #pragma unroll
    for (int m = 0; m < 2; m++) {
        #pragma unroll
        for (int p = 0; p < 4; p++) {
            #pragma unroll
            for (int r = 0; r < 4; r++) {
                int row = r0 + (2 * wm + m) * 16 + lr4 + r;
                if (row < nrows)
                    C[(size_t)row * 128 + (4 * wn + p) * 16 + lrow] = acc[m][p][r];
            }
        }
    }
}

// ---------------- MFMA LSTM: gates GEMM [N,256]@[256,512] + in-register update ----------------
// block: 32 rows, 4 waves; wave w owns gate cols {q*128 + 32w .. +31} for q=0..3
// -> all 4 gates for h-cols [32w,32w+32) are thread-local.

__global__ __launch_bounds__(256) void lstm_mfma(
    const uint4* __restrict__ Ehi, const uint4* __restrict__ Elo,
    const uint4* __restrict__ Hhi4, const uint4* __restrict__ Hlo4,
    const uint4* __restrict__ Bhi, const uint4* __restrict__ Blo,
    const float* __restrict__ bsum,
    float* __restrict__ hbuf, float* __restrict__ cbuf,
    ushort* __restrict__ hhi, ushort* __restrict__ hlo, int nrows)
{
    __shared__ ushort AsH[32][264];
    __shared__ ushort AsL[32][264];
    const int r0 = blockIdx.x * 32;
    const int tid = threadIdx.x;

    for (int v = tid; v < 32 * 32; v += 256) {
        int row = v >> 5, seg = v & 31;
        uint4 h = make_uint4(0, 0, 0, 0), L = make_uint4(0, 0, 0, 0);
        if (r0 + row < nrows) {
            if (seg < 16) {
                h = Ehi[(size_t)(r0 + row) * 16 + seg];
                L = Elo[(size_t)(r0 + row) * 16 + seg];
            } else {
                h = Hhi4[(size_t)(r0 + row) * 16 + (seg - 16)];
                L = Hlo4[(size_t)(r0 + row) * 16 + (seg - 16)];
            }
        }
        *(uint4*)&AsH[row][seg * 8] = h;
        *(uint4*)&AsL[row][seg * 8] = L;
    }
    __syncthreads();

    const int l = tid & 63, w = tid >> 6;
    const int lrow = l & 15, lk = (l >> 4) * 8, lr4 = (l >> 4) * 4;

    f32x4 acc[2][4][2];
    #pragma unroll
    for (int m = 0; m < 2; m++)
        #pragma unroll
        for (int q = 0; q < 4; q++)
            #pragma unroll
            for (int p = 0; p < 2; p++) {
                float b = bsum[q * 128 + 32 * w + 16 * p + lrow];
                acc[m][q][p] = (f32x4){b, b, b, b};
            }

    for (int kt = 0; kt < 8; kt++) {
        s8 aH[2], aL[2];
        #pragma unroll
        for (int m = 0; m < 2; m++) {
            int row = m * 16 + lrow;
            aH[m] = *(const s8*)&AsH[row][kt * 32 + lk];
            aL[m] = *(const s8*)&AsL[row][kt * 32 + lk];
        }
        #pragma unroll
        for (int q = 0; q < 4; q++) {
            #pragma unroll
            for (int p = 0; p < 2; p++) {
                int nt = 8 * q + 2 * w + p;
                uint4 bh4 = Bhi[((size_t)kt * 32 + nt) * 64 + l];
                uint4 bl4 = Blo[((size_t)kt * 32 + nt) * 64 + l];
                s8 bh = __builtin_bit_cast(s8, bh4);
                s8 bl = __builtin_bit_cast(s8, bl4);
                #pragma unroll
                for (int m = 0; m < 2; m++) {
                    acc[m][q][p] = __builtin_amdgcn_mfma_f32_16x16x32_bf16(aH[m], bh, acc[m][q][p], 0, 0, 0);
                    acc[m][q][p] = __builtin_amdgcn_mfma_f32_16x16x32_bf16(aH[m], bl, acc[m][q][p], 0, 0, 0);
                    acc[m][q][p] = __builtin_amdgcn_mfma_f32_16x16x32_bf16(aL[m], bh, acc[m][q][p], 0, 0, 0);
                }
            }
        }
    }

    #pragma unroll
    for (int m = 0; m < 2; m++) {
        #pragma unroll
        for (int p = 0; p < 2; p++) {
            int hh = 32 * w + 16 * p + lrow;
            #pragma unroll
            for (int r = 0; r < 4; r++) {
                int row = r0 + m * 16 + lr4 + r;
                if (row < nrows) {
                    size_t o = (size_t)row * HDIM + hh;
                    float gi = acc[m][0][p][r], gf = acc[m][1][p][r];
                    float gg = acc[m][2][p][r], go = acc[m][3][p][r];
                    float cold = cbuf[o];
                    float cn = sigmf(gf) * cold + sigmf(gi) * tanhf(gg);
                    float hn = sigmf(go) * tanhf(cn);
                    cbuf[o] = cn;
                    hbuf[o] = hn;
                    ushort hb = f2bf(hn);
                    hhi[o] = hb;
                    hlo[o] = f2bf(hn - bf2f(hb));
                }
            }
        }
    }
}

// ---------------- head GEMM (f32, small) ----------------

template<int WN, int R, bool BIAS>
__global__ __launch_bounds__(WN) void gemm_k128(
    const float* __restrict__ A, const float* __restrict__ W,
    const float* __restrict__ bias, float* __restrict__ C, int nrows)
{
    __shared__ float As[R][FDIM];
    int r0 = blockIdx.x * R;
    int rows_here = nrows - r0; if (rows_here > R) rows_here = R;
    if (rows_here <= 0) return;
    int j = threadIdx.x;

    const float4* A4 = (const float4*)(A + (size_t)r0 * FDIM);
    float4* As4 = (float4*)(&As[0][0]);
    int nv = rows_here * (FDIM / 4);
    for (int v = j; v < nv; v += WN) As4[v] = A4[v];
    __syncthreads();

    float b = 0.f;
    if (BIAS) b = bias[j];
    for (int rc = 0; rc < rows_here; rc += 8) {
        float acc[8];
        #pragma unroll
        for (int r = 0; r < 8; r++) acc[r] = b;
        #pragma unroll 4
        for (int k = 0; k < FDIM; k++) {
            float w = W[k * WN + j];
            #pragma unroll
            for (int r = 0; r < 8; r++) acc[r] = fmaf(As[rc + r][k], w, acc[r]);
        }
        #pragma unroll
        for (int r = 0; r < 8; r++) {
            int row = r0 + rc + r;
            if (row < nrows) C[(size_t)row * WN + j] = acc[r];
        }
    }
}

// ---------------- launch ----------------

static inline int cdiv(long long a, long long b) { return (int)((a + b - 1) / b); }

extern "C" void kernel_launch(void* const* d_in, const int* in_sizes, int n_in,
                              void* d_out, int out_size, void* d_ws, size_t ws_size,
                              hipStream_t stream) {
    const float* x_seq = (const float*)d_in[0];
    const int*   edges = (const int*)d_in[1];
    const float* W1    = (const float*)d_in[2];
    const float* b1    = (const float*)d_in[3];
    const float* W2    = (const float*)d_in[4];
    const float* b2    = (const float*)d_in[5];
    const float* Wih   = (const float*)d_in[6];
    const float* Whh   = (const float*)d_in[7];
    const float* bih   = (const float*)d_in[8];
    const float* bhh   = (const float*)d_in[9];
    const float* Wout  = (const float*)d_in[10];
    const float* bout  = (const float*)d_in[11];
    float* out = (float*)d_out;

    const int N = in_sizes[0] / (TSTEPS * FDIM);   // 50000
    const int E = in_sizes[1] / (2 * TSTEPS);      // 600000
    const int NCHUNKS = cdiv(N, SCAN_CHUNK);

    // workspace layout (floats; all offsets multiples of 4 for 16B alignment)
    float* ws = (float*)d_ws;
    size_t nPad = ((size_t)N + 255) & ~(size_t)255;
    size_t nf = (size_t)N * FDIM;
    float* dinv  = ws;
    float* xw    = dinv + nPad;          // f32 [N,128]
    float* hbuf  = xw + nf;              // f32 h
    float* cbuf  = hbuf + nf;            // f32 c
    float* h1hi  = cbuf + nf;            // ushort [N,128] views (nf/2 floats each)
    float* h1lo  = h1hi + nf / 2;
    float* embhi = h1lo + nf / 2;
    float* emblo = embhi + nf / 2;
    float* hhi   = emblo + nf / 2;
    float* hlo   = hhi + nf / 2;
    float* wcat  = hlo + nf / 2;                    // [256][512] f32
    float* bsum  = wcat + (size_t)256 * GDIM;       // [512]
    float* pW1hi = bsum + GDIM;                     // uint arrays (as float-sized slots)
    float* pW1lo = pW1hi + 8192;
    float* pW2hi = pW1lo + 8192;
    float* pW2lo = pW2hi + 8192;
    float* pWchi = pW2lo + 8192;
    float* pWclo = pWchi + 65536;
    int* deg       = (int*)(pWclo + 65536);
    int* row_start = deg + nPad;
    int* cursor    = row_start + nPad;
    int* partial   = cursor + nPad;
    int* csr_src   = partial + 256;

    const int n4 = N * 32;   // float4 count of an [N,128] f32 buffer

    prep_lstm_w<<<cdiv(256 * GDIM, 256), 256, 0, stream>>>(Wih, Whh, bih, bhh, wcat, bsum);
    pack_b<<<cdiv(4 * 8 * 256, 256), 256, 0, stream>>>(W1, 128, 128, (uint*)pW1hi, (uint*)pW1lo);
    pack_b<<<cdiv(4 * 8 * 256, 256), 256, 0, stream>>>(W2, 128, 128, (uint*)pW2hi, (uint*)pW2lo);
    pack_b<<<cdiv(8 * 32 * 256, 256), 256, 0, stream>>>(wcat, 256, GDIM, (uint*)pWchi, (uint*)pWclo);
    // zero h, c (f32) and hhi, hlo (bf16 halves)
    zero4<<<cdiv(2 * (long long)nf / 4, 256), 256, 0, stream>>>((float4*)hbuf, (int)(2 * nf / 4));
    zero4<<<cdiv((long long)nf / 4, 256), 256, 0, stream>>>((float4*)hhi, (int)(nf / 4));

    for (int t = 0; t < TSTEPS; t++) {
        const int* srcp = edges + (size_t)t * 2 * E;
        const int* dstp = srcp + E;
        const float* xt = x_seq + (size_t)t * nf;

        // ---- CSR build ----
        zero_int<<<cdiv(N, 256), 256, 0, stream>>>(deg, N);
        deg_count<<<cdiv(E, 256), 256, 0, stream>>>(dstp, deg, E);
        scan_partial<<<NCHUNKS, 256, 0, stream>>>(deg, partial, N);
        scan_offsets<<<1, 64, 0, stream>>>(partial, row_start, NCHUNKS, N);
        scan_final<<<NCHUNKS, 256, 0, stream>>>(deg, partial, row_start, cursor, N);
        deg_to_dinv<<<cdiv(N, 256), 256, 0, stream>>>(deg, dinv, N);
        edge_scatter<<<cdiv(E, 256), 256, 0, stream>>>(srcp, dstp, cursor, csr_src, E);

        // ---- layer 1: xw = x_t @ W1 (MFMA split-bf16) ----
        gemm_mfma128<false><<<cdiv(N, 64), 256, 0, stream>>>(
            xt, nullptr, nullptr, (const uint4*)pW1hi, (const uint4*)pW1lo, xw, N);
        agg_gather<<<cdiv((long long)N * 64, 256), 256, 0, stream>>>(
            row_start, csr_src, xw, dinv, b1, (uint*)h1hi, (uint*)h1lo, N);

        // ---- layer 2: xw = h1 @ W2 ----
        gemm_mfma128<true><<<cdiv(N, 64), 256, 0, stream>>>(
            nullptr, (const uint4*)h1hi, (const uint4*)h1lo,
            (const uint4*)pW2hi, (const uint4*)pW2lo, xw, N);
        agg_gather<<<cdiv((long long)N * 64, 256), 256, 0, stream>>>(
            row_start, csr_src, xw, dinv, b2, (uint*)embhi, (uint*)emblo, N);

        // ---- LSTM step ----
        lstm_mfma<<<cdiv(N, 32), 256, 0, stream>>>(
            (const uint4*)embhi, (const uint4*)emblo,
            (const uint4*)hhi, (const uint4*)hlo,
            (const uint4*)pWchi, (const uint4*)pWclo, bsum,
            hbuf, cbuf, (ushort*)hhi, (ushort*)hlo, N);
    }

    // head: out[0:N*64] = hT @ Wout + bout
    gemm_k128<ODIM, 64, true><<<cdiv(N, 64), ODIM, 0, stream>>>(hbuf, Wout, bout, out, N);
    float* out_h = out + (size_t)N * ODIM;
    float* out_c = out_h + nf;
    copy_hc<<<cdiv(n4, 256), 256, 0, stream>>>((const float4*)hbuf, (const float4*)cbuf,
                                               (float4*)out_h, (float4*)out_c, n4);
}

// Round 5
// 2310.983 us; speedup vs baseline: 9.4407x; 1.1797x over previous
//
#include <hip/hip_runtime.h>
#include <math.h>

#define TSTEPS 8
#define FDIM 128
#define HDIM 128
#define ODIM 64
#define GDIM 512
#define SCAN_CHUNK 1024

typedef __attribute__((ext_vector_type(4))) float f32x4;
typedef __attribute__((ext_vector_type(8))) short s8;

__device__ __forceinline__ float sigmf(float x) { return 1.0f / (1.0f + __expf(-x)); }

__device__ __forceinline__ ushort f2bf(float x) {
    uint u = __float_as_uint(x);
    u += 0x7FFFu + ((u >> 16) & 1u);
    return (ushort)(u >> 16);
}
__device__ __forceinline__ float bf2f(ushort h) { return __uint_as_float(((uint)h) << 16); }

// ---------------- setup kernels ----------------

__global__ void prep_lstm_w(const float* __restrict__ wih, const float* __restrict__ whh,
                            const float* __restrict__ bih, const float* __restrict__ bhh,
                            float* __restrict__ wcat, float* __restrict__ bsum) {
    int idx = blockIdx.x * 256 + threadIdx.x;
    if (idx < 256 * GDIM) {
        int k = idx >> 9;
        int col = idx & 511;
        float v = (k < HDIM) ? wih[col * HDIM + k] : whh[col * HDIM + (k - HDIM)];
        wcat[idx] = v;
        if (k == 0) bsum[col] = bih[col] + bhh[col];
    }
}

// pack B [K][NC] f32 (k-major) into MFMA-frag order, split hi/lo bf16.
// frag map: lane l, elem j -> k = kt*32 + (l>>4)*8 + j, col = nt*16 + (l&15)
__global__ void pack_b(const float* __restrict__ B, int K, int NC,
                       uint* __restrict__ hi, uint* __restrict__ lo) {
    int total = (K / 32) * (NC / 16) * 256;
    int idx = blockIdx.x * 256 + threadIdx.x;
    if (idx >= total) return;
    int d = idx & 3, l = (idx >> 2) & 63, t = idx >> 8;
    int NT = NC / 16;
    int kt = t / NT, nt = t % NT;
    int k = kt * 32 + (l >> 4) * 8 + d * 2;
    int col = nt * 16 + (l & 15);
    float va = B[(size_t)k * NC + col];
    float vb = B[(size_t)(k + 1) * NC + col];
    ushort ha = f2bf(va), hb = f2bf(vb);
    float ra = va - bf2f(ha), rb = vb - bf2f(hb);
    hi[idx] = (uint)ha | ((uint)hb << 16);
    lo[idx] = (uint)f2bf(ra) | ((uint)f2bf(rb) << 16);
}

__global__ void zero_int(int* __restrict__ p, int n) {
    int idx = blockIdx.x * 256 + threadIdx.x;
    if (idx < n) p[idx] = 0;
}

// batched over all 8 timesteps: node id = t*N + local
__global__ void deg_count8(const int* __restrict__ edges, int* __restrict__ deg,
                           int E, int N) {
    int idx = blockIdx.x * 256 + threadIdx.x;
    if (idx < TSTEPS * E) {
        int t = idx / E, e = idx - t * E;
        int d = edges[(size_t)t * 2 * E + E + e];
        atomicAdd(&deg[t * N + d], 1);
    }
}

__global__ void deg_to_dinv(const int* __restrict__ deg, float* __restrict__ dinv, int n) {
    int idx = blockIdx.x * 256 + threadIdx.x;
    if (idx < n) dinv[idx] = rsqrtf((float)(deg[idx] + 1));
}

__global__ void edge_scatter8(const int* __restrict__ edges, int* __restrict__ cursor,
                              int* __restrict__ csr_src, int E, int N) {
    int idx = blockIdx.x * 256 + threadIdx.x;
    if (idx < TSTEPS * E) {
        int t = idx / E, e = idx - t * E;
        int s = edges[(size_t)t * 2 * E + e];
        int d = edges[(size_t)t * 2 * E + E + e];
        int pos = atomicAdd(&cursor[t * N + d], 1);
        csr_src[pos] = t * N + s;   // global src id
    }
}

// ---------------- prefix scan over deg[8N] ----------------

__global__ __launch_bounds__(256) void scan_partial(const int* __restrict__ deg,
                                                    int* __restrict__ partial, int n) {
    __shared__ int s[256];
    int b = blockIdx.x, t = threadIdx.x;
    int base = b * SCAN_CHUNK + t * 4;
    int sum = 0;
    #pragma unroll
    for (int i = 0; i < 4; i++) { int idx = base + i; if (idx < n) sum += deg[idx]; }
    s[t] = sum; __syncthreads();
    for (int off = 128; off > 0; off >>= 1) {
        if (t < off) s[t] += s[t + off];
        __syncthreads();
    }
    if (t == 0) partial[b] = s[0];
}

// single block, 512 threads: exclusive-scan partial[nchunks] (nchunks <= 512)
__global__ __launch_bounds__(512) void scan_offsets1(int* __restrict__ partial,
                                                     int* __restrict__ row_start,
                                                     int nchunks, int n) {
    __shared__ int s[512];
    int t = threadIdx.x;
    int own = (t < nchunks) ? partial[t] : 0;
    s[t] = own; __syncthreads();
    for (int off = 1; off < 512; off <<= 1) {
        int add = (t >= off) ? s[t - off] : 0;
        __syncthreads();
        s[t] += add;
        __syncthreads();
    }
    if (t < nchunks) partial[t] = s[t] - own;
    if (t == 511) row_start[n] = s[511];
}

__global__ __launch_bounds__(256) void scan_final(const int* __restrict__ deg,
                                                  const int* __restrict__ partial,
                                                  int* __restrict__ row_start,
                                                  int* __restrict__ cursor, int n) {
    __shared__ int s[256];
    int b = blockIdx.x, t = threadIdx.x;
    int base = b * SCAN_CHUNK + t * 4;
    int v[4]; int local = 0;
    #pragma unroll
    for (int i = 0; i < 4; i++) { int idx = base + i; v[i] = (idx < n) ? deg[idx] : 0; local += v[i]; }
    s[t] = local; __syncthreads();
    for (int off = 1; off < 256; off <<= 1) {
        int add = (t >= off) ? s[t - off] : 0;
        __syncthreads();
        s[t] += add;
        __syncthreads();
    }
    int excl = s[t] - local + partial[b];
    #pragma unroll
    for (int i = 0; i < 4; i++) {
        int idx = base + i;
        if (idx < n) { row_start[idx] = excl; cursor[idx] = excl; }
        excl += v[i];
    }
}

// ---------------- gather aggregation over all 8N rows ----------------
// out = relu(bias + dinv[w]^2*xw[w](hi+lo) + sum coef * xw_hi[s]) -> split bf16

__global__ __launch_bounds__(256) void agg_gather8(
    const int* __restrict__ row_start, const int* __restrict__ csr_src,
    const uint* __restrict__ xh, const uint* __restrict__ xl,
    const float* __restrict__ dinv, const float* __restrict__ bias,
    uint* __restrict__ ohi, uint* __restrict__ olo, int nTotal)
{
    int w = (blockIdx.x * 256 + threadIdx.x) >> 6;
    int lane = threadIdx.x & 63;
    if (w >= nTotal) return;
    float dr = dinv[w];
    float cc = dr * dr;
    uint shv = xh[(size_t)w * 64 + lane];
    uint slv = xl[(size_t)w * 64 + lane];
    float a0 = (__uint_as_float(shv << 16) + __uint_as_float(slv << 16)) * cc;
    float a1 = (__uint_as_float(shv & 0xFFFF0000u) + __uint_as_float(slv & 0xFFFF0000u)) * cc;
    int e = row_start[w], e1 = row_start[w + 1];
    for (; e + 4 <= e1; e += 4) {
        int s0 = csr_src[e], s1 = csr_src[e + 1], s2 = csr_src[e + 2], s3 = csr_src[e + 3];
        float c0 = dinv[s0] * dr, c1 = dinv[s1] * dr, c2 = dinv[s2] * dr, c3 = dinv[s3] * dr;
        uint u0 = xh[(size_t)s0 * 64 + lane];
        uint u1 = xh[(size_t)s1 * 64 + lane];
        uint u2 = xh[(size_t)s2 * 64 + lane];
        uint u3 = xh[(size_t)s3 * 64 + lane];
        a0 = fmaf(__uint_as_float(u0 << 16), c0, a0);
        a1 = fmaf(__uint_as_float(u0 & 0xFFFF0000u), c0, a1);
        a0 = fmaf(__uint_as_float(u1 << 16), c1, a0);
        a1 = fmaf(__uint_as_float(u1 & 0xFFFF0000u), c1, a1);
        a0 = fmaf(__uint_as_float(u2 << 16), c2, a0);
        a1 = fmaf(__uint_as_float(u2 & 0xFFFF0000u), c2, a1);
        a0 = fmaf(__uint_as_float(u3 << 16), c3, a0);
        a1 = fmaf(__uint_as_float(u3 & 0xFFFF0000u), c3, a1);
    }
    for (; e < e1; e++) {
        int s = csr_src[e];
        float cf = dinv[s] * dr;
        uint u = xh[(size_t)s * 64 + lane];
        a0 = fmaf(__uint_as_float(u << 16), cf, a0);
        a1 = fmaf(__uint_as_float(u & 0xFFFF0000u), cf, a1);
    }
    float2 b = ((const float2*)bias)[lane];
    a0 = fmaxf(a0 + b.x, 0.f);
    a1 = fmaxf(a1 + b.y, 0.f);
    ushort h0 = f2bf(a0), h1 = f2bf(a1);
    ohi[(size_t)w * 64 + lane] = (uint)h0 | ((uint)h1 << 16);
    olo[(size_t)w * 64 + lane] = (uint)f2bf(a0 - bf2f(h0)) | ((uint)f2bf(a1 - bf2f(h1)) << 16);
}

// ---------------- MFMA GEMM: [M,128] @ [128,128] -> split bf16 out ----------------
// block: 64 rows x 128 cols, 4 waves; wave (wm,wn): M-tiles {2wm,2wm+1}, N-tiles {4wn..4wn+3}

template<bool SPLITSRC>
__global__ __launch_bounds__(256) void gemm_mfma128(
    const float* __restrict__ A32, const ushort* __restrict__ Ahi, const ushort* __restrict__ Alo,
    const uint4* __restrict__ Bhi, const uint4* __restrict__ Blo,
    ushort* __restrict__ Chi, ushort* __restrict__ Clo, int nrows)
{
    __shared__ ushort AsH[64][136];
    __shared__ ushort AsL[64][136];
    const int r0 = blockIdx.x * 64;
    const int tid = threadIdx.x;

    if (SPLITSRC) {
        for (int v = tid; v < 64 * 16; v += 256) {
            int row = v >> 4, seg = v & 15;
            uint4 h = make_uint4(0, 0, 0, 0), L = make_uint4(0, 0, 0, 0);
            if (r0 + row < nrows) {
                h = *(const uint4*)(Ahi + (size_t)(r0 + row) * 128 + seg * 8);
                L = *(const uint4*)(Alo + (size_t)(r0 + row) * 128 + seg * 8);
            }
            *(uint4*)&AsH[row][seg * 8] = h;
            *(uint4*)&AsL[row][seg * 8] = L;
        }
    } else {
        for (int v = tid; v < 64 * 16; v += 256) {
            int row = v >> 4, seg = v & 15;
            float4 a = make_float4(0.f, 0.f, 0.f, 0.f), b = a;
            if (r0 + row < nrows) {
                const float4* src = (const float4*)A32 + (size_t)(r0 + row) * 32 + seg * 2;
                a = src[0]; b = src[1];
            }
            float vv[8] = {a.x, a.y, a.z, a.w, b.x, b.y, b.z, b.w};
            uint hh[4], ll[4];
            #pragma unroll
            for (int i = 0; i < 4; i++) {
                float v0 = vv[2 * i], v1 = vv[2 * i + 1];
                ushort h0 = f2bf(v0), h1 = f2bf(v1);
                hh[i] = (uint)h0 | ((uint)h1 << 16);
                ll[i] = (uint)f2bf(v0 - bf2f(h0)) | ((uint)f2bf(v1 - bf2f(h1)) << 16);
            }
            *(uint4*)&AsH[row][seg * 8] = make_uint4(hh[0], hh[1], hh[2], hh[3]);
            *(uint4*)&AsL[row][seg * 8] = make_uint4(ll[0], ll[1], ll[2], ll[3]);
        }
    }
    __syncthreads();

    const int l = tid & 63, w = tid >> 6;
    const int wm = w & 1, wn = w >> 1;
    const int lrow = l & 15, lk = (l >> 4) * 8;

    f32x4 acc[2][4];
    #pragma unroll
    for (int m = 0; m < 2; m++)
        #pragma unroll
        for (int p = 0; p < 4; p++) acc[m][p] = (f32x4){0.f, 0.f, 0.f, 0.f};

    for (int kt = 0; kt < 4; kt++) {
        s8 aH[2], aL[2];
        #pragma unroll
        for (int m = 0; m < 2; m++) {
            int row = (2 * wm + m) * 16 + lrow;
            aH[m] = *(const s8*)&AsH[row][kt * 32 + lk];
            aL[m] = *(const s8*)&AsL[row][kt * 32 + lk];
        }
        #pragma unroll
        for (int p = 0; p < 4; p++) {
            int nt = 4 * wn + p;
            uint4 bh4 = Bhi[(kt * 8 + nt) * 64 + l];
            uint4 bl4 = Blo[(kt * 8 + nt) * 64 + l];
            s8 bh = __builtin_bit_cast(s8, bh4);
            s8 bl = __builtin_bit_cast(s8, bl4);
            #pragma unroll
            for (int m = 0; m < 2; m++) {
                acc[m][p] = __builtin_amdgcn_mfma_f32_16x16x32_bf16(aH[m], bh, acc[m][p], 0, 0, 0);
                acc[m][p] = __builtin_amdgcn_mfma_f32_16x16x32_bf16(aH[m], bl, acc[m][p], 0, 0, 0);
                acc[m][p] = __builtin_amdgcn_mfma_f32_16x16x32_bf16(aL[m], bh, acc[m][p], 0, 0, 0);
            }
        }
    }

    const int lr4 = (l >> 4) * 4;
    #pragma unroll
    for (int m = 0; m < 2; m++) {
        #pragma unroll
        for (int p = 0; p < 4; p++) {
            int col = (4 * wn + p) * 16 + lrow;
            #pragma unroll
            for (int r = 0; r < 4; r++) {
                int row = r0 + (2 * wm + m) * 16 + lr4 + r;
                if (row < nrows) {
                    float v = acc[m][p][r];
                    ushort h = f2bf(v);
                    Chi[(size_t)row * 128 + col] = h;
                    Clo[(size_t)row * 128 + col] = f2bf(v - bf2f(h));
                }
            }
        }
    }
}

// ---------------- one-kernel LSTM over all 8 timesteps + fused head ----------------
// block: 32 rows, 4 waves. Wave w owns gate cols {q*128 + 32w..+31}, q=0..3.
// h/c in registers; h's bf16 split written to LDS for the next timestep.

__global__ __launch_bounds__(256) void lstm_all(
    const ushort* __restrict__ Ehi, const ushort* __restrict__ Elo,
    const uint4* __restrict__ Bhi, const uint4* __restrict__ Blo,
    const float* __restrict__ bsum,
    const uint4* __restrict__ Whi, const uint4* __restrict__ Wlo,
    const float* __restrict__ bout,
    float* __restrict__ outp, float* __restrict__ outh, float* __restrict__ outc,
    int nrows)
{
    __shared__ ushort AsH[32][264];
    __shared__ ushort AsL[32][264];
    const int r0 = blockIdx.x * 32;
    const int tid = threadIdx.x;
    const int l = tid & 63, w = tid >> 6;
    const int lrow = l & 15, lk = (l >> 4) * 8, lr4 = (l >> 4) * 4;

    // zero both LDS arrays (h cols start at 0)
    for (int v = tid; v < 32 * 264 / 2; v += 256) {
        ((uint*)AsH)[v] = 0u;
        ((uint*)AsL)[v] = 0u;
    }

    float breg[4][2];
    #pragma unroll
    for (int q = 0; q < 4; q++)
        #pragma unroll
        for (int p = 0; p < 2; p++)
            breg[q][p] = bsum[q * 128 + 32 * w + 16 * p + lrow];

    float creg[2][2][4], hreg[2][2][4];
    #pragma unroll
    for (int m = 0; m < 2; m++)
        #pragma unroll
        for (int p = 0; p < 2; p++)
            #pragma unroll
            for (int r = 0; r < 4; r++) { creg[m][p][r] = 0.f; hreg[m][p][r] = 0.f; }

    #pragma unroll 1
    for (int t = 0; t < TSTEPS; t++) {
        // stage emb_t into cols 0..127
        for (int v = tid; v < 32 * 16; v += 256) {
            int row = v >> 4, seg = v & 15;
            uint4 h = make_uint4(0, 0, 0, 0), L = make_uint4(0, 0, 0, 0);
            if (r0 + row < nrows) {
                size_t g = ((size_t)t * nrows + r0 + row) * 128 + seg * 8;
                h = *(const uint4*)(Ehi + g);
                L = *(const uint4*)(Elo + g);
            }
            *(uint4*)&AsH[row][seg * 8] = h;
            *(uint4*)&AsL[row][seg * 8] = L;
        }
        __syncthreads();

        f32x4 acc[2][4][2];
        #pragma unroll
        for (int m = 0; m < 2; m++)
            #pragma unroll
            for (int q = 0; q < 4; q++)
                #pragma unroll
                for (int p = 0; p < 2; p++) {
                    float b = breg[q][p];
                    acc[m][q][p] = (f32x4){b, b, b, b};
                }

        #pragma unroll
        for (int kt = 0; kt < 8; kt++) {
            s8 aH[2], aL[2];
            #pragma unroll
            for (int m = 0; m < 2; m++) {
                int row = m * 16 + lrow;
                aH[m] = *(const s8*)&AsH[row][kt * 32 + lk];
                aL[m] = *(const s8*)&AsL[row][kt * 32 + lk];
            }
            #pragma unroll
            for (int q = 0; q < 4; q++) {
                #pragma unroll
                for (int p = 0; p < 2; p++) {
                    int nt = 8 * q + 2 * w + p;
                    uint4 bh4 = Bhi[((size_t)kt * 32 + nt) * 64 + l];
                    uint4 bl4 = Blo[((size_t)kt * 32 + nt) * 64 + l];
                    s8 bh = __builtin_bit_cast(s8, bh4);
                    s8 bl = __builtin_bit_cast(s8, bl4);
                    #pragma unroll
                    for (int m = 0; m < 2; m++) {
                        acc[m][q][p] = __builtin_amdgcn_mfma_f32_16x16x32_bf16(aH[m], bh, acc[m][q][p], 0, 0, 0);
                        acc[m][q][p] = __builtin_amdgcn_mfma_f32_16x16x32_bf16(aH[m], bl, acc[m][q][p], 0, 0, 0);
                        acc[m][q][p] = __builtin_amdgcn_mfma_f32_16x16x32_bf16(aL[m], bh, acc[m][q][p], 0, 0, 0);
                    }
                }
            }
        }
        __syncthreads();   // all LDS reads for this t done

        // update c,h; write new h (bf16 split) into LDS cols 128..255
        #pragma unroll
        for (int m = 0; m < 2; m++) {
            #pragma unroll
            for (int p = 0; p < 2; p++) {
                int hh = 32 * w + 16 * p + lrow;
                #pragma unroll
                for (int r = 0; r < 4; r++) {
                    int row = m * 16 + lr4 + r;
                    float gi = acc[m][0][p][r], gf = acc[m][1][p][r];
                    float gg = acc[m][2][p][r], go = acc[m][3][p][r];
                    float cn = sigmf(gf) * creg[m][p][r] + sigmf(gi) * tanhf(gg);
                    float hn = sigmf(go) * tanhf(cn);
                    creg[m][p][r] = cn;
                    hreg[m][p][r] = hn;
                    ushort hb = f2bf(hn);
                    AsH[row][128 + hh] = hb;
                    AsL[row][128 + hh] = f2bf(hn - bf2f(hb));
                }
            }
        }
        // no sync here: next iteration's emb staging touches cols 0..127 only,
        // and the next MFMA reads happen after the staging sync.
    }
    __syncthreads();   // h_T ready in LDS for the head GEMM

    // head: out[32,64] = h_T @ Wout + bout ; wave w does n-tile w
    f32x4 hacc[2];
    {
        float b = bout[w * 16 + lrow];
        hacc[0] = (f32x4){b, b, b, b};
        hacc[1] = hacc[0];
    }
    #pragma unroll
    for (int kt = 0; kt < 4; kt++) {
        s8 aH[2], aL[2];
        #pragma unroll
        for (int m = 0; m < 2; m++) {
            int row = m * 16 + lrow;
            aH[m] = *(const s8*)&AsH[row][128 + kt * 32 + lk];
            aL[m] = *(const s8*)&AsL[row][128 + kt * 32 + lk];
        }
        uint4 bh4 = Whi[(kt * 4 + w) * 64 + l];
        uint4 bl4 = Wlo[(kt * 4 + w) * 64 + l];
        s8 bh = __builtin_bit_cast(s8, bh4);
        s8 bl = __builtin_bit_cast(s8, bl4);
        #pragma unroll
        for (int m = 0; m < 2; m++) {
            hacc[m] = __builtin_amdgcn_mfma_f32_16x16x32_bf16(aH[m], bh, hacc[m], 0, 0, 0);
            hacc[m] = __builtin_amdgcn_mfma_f32_16x16x32_bf16(aH[m], bl, hacc[m], 0, 0, 0);
            hacc[m] = __builtin_amdgcn_mfma_f32_16x16x32_bf16(aL[m], bh, hacc[m], 0, 0, 0);
        }
    }

    #pragma unroll
    for (int m = 0; m < 2; m++) {
        #pragma unroll
        for (int r = 0; r < 4; r++) {
            int row = r0 + m * 16 + lr4 + r;
            if (row < nrows)
                outp[(size_t)row * ODIM + w * 16 + lrow] = hacc[m][r];
        }
        #pragma unroll
        for (int p = 0; p < 2; p++) {
            int hh = 32 * w + 16 * p + lrow;
            #pragma unroll
            for (int r = 0; r < 4; r++) {
                int row = r0 + m * 16 + lr4 + r;
                if (row < nrows) {
                    outh[(size_t)row * HDIM + hh] = hreg[m][p][r];
                    outc[(size_t)row * HDIM + hh] = creg[m][p][r];
                }
            }
        }
    }
}

// ---------------- launch ----------------

static inline int cdiv(long long a, long long b) { return (int)((a + b - 1) / b); }

extern "C" void kernel_launch(void* const* d_in, const int* in_sizes, int n_in,
                              void* d_out, int out_size, void* d_ws, size_t ws_size,
                              hipStream_t stream) {
    const float* x_seq = (const float*)d_in[0];
    const int*   edges = (const int*)d_in[1];
    const float* W1    = (const float*)d_in[2];
    const float* b1    = (const float*)d_in[3];
    const float* W2    = (const float*)d_in[4];
    const float* b2    = (const float*)d_in[5];
    const float* Wih   = (const float*)d_in[6];
    const float* Whh   = (const float*)d_in[7];
    const float* bih   = (const float*)d_in[8];
    const float* bhh   = (const float*)d_in[9];
    const float* Wout  = (const float*)d_in[10];
    const float* bout  = (const float*)d_in[11];
    float* out = (float*)d_out;

    const int N = in_sizes[0] / (TSTEPS * FDIM);   // 50000
    const int E = in_sizes[1] / (2 * TSTEPS);      // 600000
    const int NT8 = TSTEPS * N;                    // 400000
    const size_t NP = ((size_t)NT8 + 255) & ~(size_t)255;
    const int NCHUNKS = cdiv(NT8, SCAN_CHUNK);

    // workspace layout
    float* ws = (float*)d_ws;
    float* dinv = ws;                              // NP f32
    float* wcat = dinv + NP;                       // 256*512
    float* bsum = wcat + 131072;                   // 512
    uint* pW1hi = (uint*)(bsum + 512);             // 8192 each
    uint* pW1lo = pW1hi + 8192;
    uint* pW2hi = pW1lo + 8192;
    uint* pW2lo = pW2hi + 8192;
    uint* pWchi = pW2lo + 8192;                    // 65536 each
    uint* pWclo = pWchi + 65536;
    uint* pWohi = pWclo + 65536;                   // 4096 each
    uint* pWolo = pWohi + 4096;
    ushort* xwhi = (ushort*)(pWolo + 4096);        // [8N][128] each
    ushort* xwlo = xwhi + (size_t)NT8 * 128;
    ushort* h1hi = xwlo + (size_t)NT8 * 128;
    ushort* h1lo = h1hi + (size_t)NT8 * 128;
    ushort* ehi  = h1lo + (size_t)NT8 * 128;
    ushort* elo  = ehi  + (size_t)NT8 * 128;
    int* deg       = (int*)(elo + (size_t)NT8 * 128);
    int* row_start = deg + NP;
    int* cursor    = row_start + NP;
    int* partial   = cursor + NP;                  // 512
    int* csr_src   = partial + 512;                // 8E

    // weights prep
    prep_lstm_w<<<cdiv(256 * GDIM, 256), 256, 0, stream>>>(Wih, Whh, bih, bhh, wcat, bsum);
    pack_b<<<32, 256, 0, stream>>>(W1, 128, 128, pW1hi, pW1lo);
    pack_b<<<32, 256, 0, stream>>>(W2, 128, 128, pW2hi, pW2lo);
    pack_b<<<256, 256, 0, stream>>>(wcat, 256, GDIM, pWchi, pWclo);
    pack_b<<<16, 256, 0, stream>>>(Wout, 128, ODIM, pWohi, pWolo);

    // batched CSR build (all 8 timesteps as one disjoint graph)
    zero_int<<<cdiv(NP, 256), 256, 0, stream>>>(deg, (int)NP);
    deg_count8<<<cdiv((long long)TSTEPS * E, 256), 256, 0, stream>>>(edges, deg, E, N);
    scan_partial<<<NCHUNKS, 256, 0, stream>>>(deg, partial, NT8);
    scan_offsets1<<<1, 512, 0, stream>>>(partial, row_start, NCHUNKS, NT8);
    scan_final<<<NCHUNKS, 256, 0, stream>>>(deg, partial, row_start, cursor, NT8);
    deg_to_dinv<<<cdiv(NT8, 256), 256, 0, stream>>>(deg, dinv, NT8);
    edge_scatter8<<<cdiv((long long)TSTEPS * E, 256), 256, 0, stream>>>(edges, cursor, csr_src, E, N);

    // layer 1 (batched over all t)
    gemm_mfma128<false><<<cdiv(NT8, 64), 256, 0, stream>>>(
        x_seq, nullptr, nullptr, (const uint4*)pW1hi, (const uint4*)pW1lo, xwhi, xwlo, NT8);
    agg_gather8<<<cdiv((long long)NT8 * 64, 256), 256, 0, stream>>>(
        row_start, csr_src, (const uint*)xwhi, (const uint*)xwlo, dinv, b1,
        (uint*)h1hi, (uint*)h1lo, NT8);

    // layer 2 (batched)
    gemm_mfma128<true><<<cdiv(NT8, 64), 256, 0, stream>>>(
        nullptr, h1hi, h1lo, (const uint4*)pW2hi, (const uint4*)pW2lo, xwhi, xwlo, NT8);
    agg_gather8<<<cdiv((long long)NT8 * 64, 256), 256, 0, stream>>>(
        row_start, csr_src, (const uint*)xwhi, (const uint*)xwlo, dinv, b2,
        (uint*)ehi, (uint*)elo, NT8);

    // LSTM over all timesteps + fused head and h/c output
    float* out_h = out + (size_t)N * ODIM;
    float* out_c = out_h + (size_t)N * HDIM;
    lstm_all<<<cdiv(N, 32), 256, 0, stream>>>(
        ehi, elo, (const uint4*)pWchi, (const uint4*)pWclo, bsum,
        (const uint4*)pWohi, (const uint4*)pWolo, bout,
        out, out_h, out_c, N);
}

// Round 6
// 2100.451 us; speedup vs baseline: 10.3869x; 1.1002x over previous
//
#include <hip/hip_runtime.h>
#include <math.h>

#define TSTEPS 8
#define FDIM 128
#define HDIM 128
#define ODIM 64
#define GDIM 512
#define SCAN_CHUNK 1024

typedef __attribute__((ext_vector_type(4))) float f32x4;
typedef __attribute__((ext_vector_type(8))) short s8;

__device__ __forceinline__ float sigmf(float x) { return 1.0f / (1.0f + __expf(-x)); }

__device__ __forceinline__ ushort f2bf(float x) {
    uint u = __float_as_uint(x);
    u += 0x7FFFu + ((u >> 16) & 1u);
    return (ushort)(u >> 16);
}
__device__ __forceinline__ float bf2f(ushort h) { return __uint_as_float(((uint)h) << 16); }

// ---------------- setup kernels ----------------

__global__ void prep_lstm_w(const float* __restrict__ wih, const float* __restrict__ whh,
                            const float* __restrict__ bih, const float* __restrict__ bhh,
                            float* __restrict__ wcat, float* __restrict__ bsum) {
    int idx = blockIdx.x * 256 + threadIdx.x;
    if (idx < 256 * GDIM) {
        int k = idx >> 9;
        int col = idx & 511;
        float v = (k < HDIM) ? wih[col * HDIM + k] : whh[col * HDIM + (k - HDIM)];
        wcat[idx] = v;
        if (k == 0) bsum[col] = bih[col] + bhh[col];
    }
}

// pack B [K][NC] f32 (k-major) into MFMA-frag order, split hi/lo bf16.
// frag map: lane l, elem j -> k = kt*32 + (l>>4)*8 + j, col = nt*16 + (l&15)
__global__ void pack_b(const float* __restrict__ B, int K, int NC,
                       uint* __restrict__ hi, uint* __restrict__ lo) {
    int total = (K / 32) * (NC / 16) * 256;
    int idx = blockIdx.x * 256 + threadIdx.x;
    if (idx >= total) return;
    int d = idx & 3, l = (idx >> 2) & 63, t = idx >> 8;
    int NT = NC / 16;
    int kt = t / NT, nt = t % NT;
    int k = kt * 32 + (l >> 4) * 8 + d * 2;
    int col = nt * 16 + (l & 15);
    float va = B[(size_t)k * NC + col];
    float vb = B[(size_t)(k + 1) * NC + col];
    ushort ha = f2bf(va), hb = f2bf(vb);
    float ra = va - bf2f(ha), rb = vb - bf2f(hb);
    hi[idx] = (uint)ha | ((uint)hb << 16);
    lo[idx] = (uint)f2bf(ra) | ((uint)f2bf(rb) << 16);
}

__global__ void zero_int(int* __restrict__ p, int n) {
    int idx = blockIdx.x * 256 + threadIdx.x;
    if (idx < n) p[idx] = 0;
}

// batched over all 8 timesteps: node id = t*N + local
__global__ void deg_count8(const int* __restrict__ edges, int* __restrict__ deg,
                           int E, int N) {
    int idx = blockIdx.x * 256 + threadIdx.x;
    if (idx < TSTEPS * E) {
        int t = idx / E, e = idx - t * E;
        int d = edges[(size_t)t * 2 * E + E + e];
        atomicAdd(&deg[t * N + d], 1);
    }
}

__global__ void deg_to_dinv(const int* __restrict__ deg, float* __restrict__ dinv, int n) {
    int idx = blockIdx.x * 256 + threadIdx.x;
    if (idx < n) dinv[idx] = rsqrtf((float)(deg[idx] + 1));
}

__global__ void edge_scatter8(const int* __restrict__ edges, int* __restrict__ cursor,
                              int* __restrict__ csr_src, int E, int N) {
    int idx = blockIdx.x * 256 + threadIdx.x;
    if (idx < TSTEPS * E) {
        int t = idx / E, e = idx - t * E;
        int s = edges[(size_t)t * 2 * E + e];
        int d = edges[(size_t)t * 2 * E + E + e];
        int pos = atomicAdd(&cursor[t * N + d], 1);
        csr_src[pos] = t * N + s;   // global src id
    }
}

// ---------------- prefix scan over deg[8N] ----------------

__global__ __launch_bounds__(256) void scan_partial(const int* __restrict__ deg,
                                                    int* __restrict__ partial, int n) {
    __shared__ int s[256];
    int b = blockIdx.x, t = threadIdx.x;
    int base = b * SCAN_CHUNK + t * 4;
    int sum = 0;
    #pragma unroll
    for (int i = 0; i < 4; i++) { int idx = base + i; if (idx < n) sum += deg[idx]; }
    s[t] = sum; __syncthreads();
    for (int off = 128; off > 0; off >>= 1) {
        if (t < off) s[t] += s[t + off];
        __syncthreads();
    }
    if (t == 0) partial[b] = s[0];
}

// single block, 512 threads: exclusive-scan partial[nchunks] (nchunks <= 512)
__global__ __launch_bounds__(512) void scan_offsets1(int* __restrict__ partial,
                                                     int* __restrict__ row_start,
                                                     int nchunks, int n) {
    __shared__ int s[512];
    int t = threadIdx.x;
    int own = (t < nchunks) ? partial[t] : 0;
    s[t] = own; __syncthreads();
    for (int off = 1; off < 512; off <<= 1) {
        int add = (t >= off) ? s[t - off] : 0;
        __syncthreads();
        s[t] += add;
        __syncthreads();
    }
    if (t < nchunks) partial[t] = s[t] - own;
    if (t == 511) row_start[n] = s[511];
}

__global__ __launch_bounds__(256) void scan_final(const int* __restrict__ deg,
                                                  const int* __restrict__ partial,
                                                  int* __restrict__ row_start,
                                                  int* __restrict__ cursor, int n) {
    __shared__ int s[256];
    int b = blockIdx.x, t = threadIdx.x;
    int base = b * SCAN_CHUNK + t * 4;
    int v[4]; int local = 0;
    #pragma unroll
    for (int i = 0; i < 4; i++) { int idx = base + i; v[i] = (idx < n) ? deg[idx] : 0; local += v[i]; }
    s[t] = local; __syncthreads();
    for (int off = 1; off < 256; off <<= 1) {
        int add = (t >= off) ? s[t - off] : 0;
        __syncthreads();
        s[t] += add;
        __syncthreads();
    }
    int excl = s[t] - local + partial[b];
    #pragma unroll
    for (int i = 0; i < 4; i++) {
        int idx = base + i;
        if (idx < n) { row_start[idx] = excl; cursor[idx] = excl; }
        excl += v[i];
    }
}

// ---------------- gather aggregation over all 8N rows ----------------

__global__ __launch_bounds__(256) void agg_gather8(
    const int* __restrict__ row_start, const int* __restrict__ csr_src,
    const uint* __restrict__ xh, const uint* __restrict__ xl,
    const float* __restrict__ dinv, const float* __restrict__ bias,
    uint* __restrict__ ohi, uint* __restrict__ olo, int nTotal)
{
    int w = (blockIdx.x * 256 + threadIdx.x) >> 6;
    int lane = threadIdx.x & 63;
    if (w >= nTotal) return;
    float dr = dinv[w];
    float cc = dr * dr;
    uint shv = xh[(size_t)w * 64 + lane];
    uint slv = xl[(size_t)w * 64 + lane];
    float a0 = (__uint_as_float(shv << 16) + __uint_as_float(slv << 16)) * cc;
    float a1 = (__uint_as_float(shv & 0xFFFF0000u) + __uint_as_float(slv & 0xFFFF0000u)) * cc;
    int e = row_start[w], e1 = row_start[w + 1];
    for (; e + 4 <= e1; e += 4) {
        int s0 = csr_src[e], s1 = csr_src[e + 1], s2 = csr_src[e + 2], s3 = csr_src[e + 3];
        float c0 = dinv[s0] * dr, c1 = dinv[s1] * dr, c2 = dinv[s2] * dr, c3 = dinv[s3] * dr;
        uint u0 = xh[(size_t)s0 * 64 + lane];
        uint u1 = xh[(size_t)s1 * 64 + lane];
        uint u2 = xh[(size_t)s2 * 64 + lane];
        uint u3 = xh[(size_t)s3 * 64 + lane];
        a0 = fmaf(__uint_as_float(u0 << 16), c0, a0);
        a1 = fmaf(__uint_as_float(u0 & 0xFFFF0000u), c0, a1);
        a0 = fmaf(__uint_as_float(u1 << 16), c1, a0);
        a1 = fmaf(__uint_as_float(u1 & 0xFFFF0000u), c1, a1);
        a0 = fmaf(__uint_as_float(u2 << 16), c2, a0);
        a1 = fmaf(__uint_as_float(u2 & 0xFFFF0000u), c2, a1);
        a0 = fmaf(__uint_as_float(u3 << 16), c3, a0);
        a1 = fmaf(__uint_as_float(u3 & 0xFFFF0000u), c3, a1);
    }
    for (; e < e1; e++) {
        int s = csr_src[e];
        float cf = dinv[s] * dr;
        uint u = xh[(size_t)s * 64 + lane];
        a0 = fmaf(__uint_as_float(u << 16), cf, a0);
        a1 = fmaf(__uint_as_float(u & 0xFFFF0000u), cf, a1);
    }
    float2 b = ((const float2*)bias)[lane];
    a0 = fmaxf(a0 + b.x, 0.f);
    a1 = fmaxf(a1 + b.y, 0.f);
    ushort h0 = f2bf(a0), h1 = f2bf(a1);
    ohi[(size_t)w * 64 + lane] = (uint)h0 | ((uint)h1 << 16);
    olo[(size_t)w * 64 + lane] = (uint)f2bf(a0 - bf2f(h0)) | ((uint)f2bf(a1 - bf2f(h1)) << 16);
}

// ---------------- MFMA GEMM: [M,128] @ [128,128] -> split bf16 out ----------------

template<bool SPLITSRC>
__global__ __launch_bounds__(256) void gemm_mfma128(
    const float* __restrict__ A32, const ushort* __restrict__ Ahi, const ushort* __restrict__ Alo,
    const uint4* __restrict__ Bhi, const uint4* __restrict__ Blo,
    ushort* __restrict__ Chi, ushort* __restrict__ Clo, int nrows)
{
    __shared__ ushort AsH[64][136];
    __shared__ ushort AsL[64][136];
    const int r0 = blockIdx.x * 64;
    const int tid = threadIdx.x;

    if (SPLITSRC) {
        for (int v = tid; v < 64 * 16; v += 256) {
            int row = v >> 4, seg = v & 15;
            uint4 h = make_uint4(0, 0, 0, 0), L = make_uint4(0, 0, 0, 0);
            if (r0 + row < nrows) {
                h = *(const uint4*)(Ahi + (size_t)(r0 + row) * 128 + seg * 8);
                L = *(const uint4*)(Alo + (size_t)(r0 + row) * 128 + seg * 8);
            }
            *(uint4*)&AsH[row][seg * 8] = h;
            *(uint4*)&AsL[row][seg * 8] = L;
        }
    } else {
        for (int v = tid; v < 64 * 16; v += 256) {
            int row = v >> 4, seg = v & 15;
            float4 a = make_float4(0.f, 0.f, 0.f, 0.f), b = a;
            if (r0 + row < nrows) {
                const float4* src = (const float4*)A32 + (size_t)(r0 + row) * 32 + seg * 2;
                a = src[0]; b = src[1];
            }
            float vv[8] = {a.x, a.y, a.z, a.w, b.x, b.y, b.z, b.w};
            uint hh[4], ll[4];
            #pragma unroll
            for (int i = 0; i < 4; i++) {
                float v0 = vv[2 * i], v1 = vv[2 * i + 1];
                ushort h0 = f2bf(v0), h1 = f2bf(v1);
                hh[i] = (uint)h0 | ((uint)h1 << 16);
                ll[i] = (uint)f2bf(v0 - bf2f(h0)) | ((uint)f2bf(v1 - bf2f(h1)) << 16);
            }
            *(uint4*)&AsH[row][seg * 8] = make_uint4(hh[0], hh[1], hh[2], hh[3]);
            *(uint4*)&AsL[row][seg * 8] = make_uint4(ll[0], ll[1], ll[2], ll[3]);
        }
    }
    __syncthreads();

    const int l = tid & 63, w = tid >> 6;
    const int wm = w & 1, wn = w >> 1;
    const int lrow = l & 15, lk = (l >> 4) * 8;

    f32x4 acc[2][4];
    #pragma unroll
    for (int m = 0; m < 2; m++)
        #pragma unroll
        for (int p = 0; p < 4; p++) acc[m][p] = (f32x4){0.f, 0.f, 0.f, 0.f};

    for (int kt = 0; kt < 4; kt++) {
        s8 aH[2], aL[2];
        #pragma unroll
        for (int m = 0; m < 2; m++) {
            int row = (2 * wm + m) * 16 + lrow;
            aH[m] = *(const s8*)&AsH[row][kt * 32 + lk];
            aL[m] = *(const s8*)&AsL[row][kt * 32 + lk];
        }
        #pragma unroll
        for (int p = 0; p < 4; p++) {
            int nt = 4 * wn + p;
            uint4 bh4 = Bhi[(kt * 8 + nt) * 64 + l];
            uint4 bl4 = Blo[(kt * 8 + nt) * 64 + l];
            s8 bh = __builtin_bit_cast(s8, bh4);
            s8 bl = __builtin_bit_cast(s8, bl4);
            #pragma unroll
            for (int m = 0; m < 2; m++) {
                acc[m][p] = __builtin_amdgcn_mfma_f32_16x16x32_bf16(aH[m], bh, acc[m][p], 0, 0, 0);
                acc[m][p] = __builtin_amdgcn_mfma_f32_16x16x32_bf16(aH[m], bl, acc[m][p], 0, 0, 0);
                acc[m][p] = __builtin_amdgcn_mfma_f32_16x16x32_bf16(aL[m], bh, acc[m][p], 0, 0, 0);
            }
        }
    }

    const int lr4 = (l >> 4) * 4;
    #pragma unroll
    for (int m = 0; m < 2; m++) {
        #pragma unroll
        for (int p = 0; p < 4; p++) {
            int col = (4 * wn + p) * 16 + lrow;
            #pragma unroll
            for (int r = 0; r < 4; r++) {
                int row = r0 + (2 * wm + m) * 16 + lr4 + r;
                if (row < nrows) {
                    float v = acc[m][p][r];
                    ushort h = f2bf(v);
                    Chi[(size_t)row * 128 + col] = h;
                    Clo[(size_t)row * 128 + col] = f2bf(v - bf2f(h));
                }
            }
        }
    }
}

// ---------------- per-timestep LSTM: gates GEMM + state update; LAST fuses head ----------------
// block: 32 rows, 4 waves. Wave w owns gate cols {q*128 + 32w..+31}, q=0..3.
// Ehi/Elo passed pre-offset to timestep t. h kept ONLY as split bf16 in HBM; c as f32.

template<bool LAST>
__global__ __launch_bounds__(256) void lstm_step_t(
    const ushort* __restrict__ Ehi, const ushort* __restrict__ Elo,
    ushort* __restrict__ Hhi, ushort* __restrict__ Hlo,
    const uint4* __restrict__ Bhi, const uint4* __restrict__ Blo,
    const float* __restrict__ bsum, float* __restrict__ cbuf,
    const uint4* __restrict__ Whi, const uint4* __restrict__ Wlo,
    const float* __restrict__ bout,
    float* __restrict__ outp, float* __restrict__ outh, float* __restrict__ outc,
    int nrows)
{
    __shared__ ushort AsH[32][264];
    __shared__ ushort AsL[32][264];
    const int r0 = blockIdx.x * 32;
    const int tid = threadIdx.x;
    const int l = tid & 63, w = tid >> 6;
    const int lrow = l & 15, lk = (l >> 4) * 8, lr4 = (l >> 4) * 4;

    // stage emb_t (cols 0..127) and h_prev (cols 128..255)
    for (int v = tid; v < 32 * 32; v += 256) {
        int row = v >> 5, seg = v & 31;
        uint4 h = make_uint4(0, 0, 0, 0), L = make_uint4(0, 0, 0, 0);
        if (r0 + row < nrows) {
            if (seg < 16) {
                size_t g = (size_t)(r0 + row) * 128 + seg * 8;
                h = *(const uint4*)(Ehi + g);
                L = *(const uint4*)(Elo + g);
            } else {
                size_t g = (size_t)(r0 + row) * 128 + (seg - 16) * 8;
                h = *(const uint4*)(Hhi + g);
                L = *(const uint4*)(Hlo + g);
            }
        }
        *(uint4*)&AsH[row][seg * 8] = h;
        *(uint4*)&AsL[row][seg * 8] = L;
    }
    __syncthreads();

    f32x4 acc[2][4][2];
    #pragma unroll
    for (int m = 0; m < 2; m++)
        #pragma unroll
        for (int q = 0; q < 4; q++)
            #pragma unroll
            for (int p = 0; p < 2; p++) {
                float b = bsum[q * 128 + 32 * w + 16 * p + lrow];
                acc[m][q][p] = (f32x4){b, b, b, b};
            }

    #pragma unroll
    for (int kt = 0; kt < 8; kt++) {
        s8 aH[2], aL[2];
        #pragma unroll
        for (int m = 0; m < 2; m++) {
            int row = m * 16 + lrow;
            aH[m] = *(const s8*)&AsH[row][kt * 32 + lk];
            aL[m] = *(const s8*)&AsL[row][kt * 32 + lk];
        }
        #pragma unroll
        for (int q = 0; q < 4; q++) {
            #pragma unroll
            for (int p = 0; p < 2; p++) {
                int nt = 8 * q + 2 * w + p;
                uint4 bh4 = Bhi[((size_t)kt * 32 + nt) * 64 + l];
                uint4 bl4 = Blo[((size_t)kt * 32 + nt) * 64 + l];
                s8 bh = __builtin_bit_cast(s8, bh4);
                s8 bl = __builtin_bit_cast(s8, bl4);
                #pragma unroll
                for (int m = 0; m < 2; m++) {
                    acc[m][q][p] = __builtin_amdgcn_mfma_f32_16x16x32_bf16(aH[m], bh, acc[m][q][p], 0, 0, 0);
                    acc[m][q][p] = __builtin_amdgcn_mfma_f32_16x16x32_bf16(aH[m], bl, acc[m][q][p], 0, 0, 0);
                    acc[m][q][p] = __builtin_amdgcn_mfma_f32_16x16x32_bf16(aL[m], bh, acc[m][q][p], 0, 0, 0);
                }
            }
        }
    }
    if (LAST) __syncthreads();   // done reading h_prev from LDS before overwrite

    // update c,h; write h split to HBM (and LDS if LAST, for the head GEMM)
    #pragma unroll
    for (int m = 0; m < 2; m++) {
        #pragma unroll
        for (int p = 0; p < 2; p++) {
            int hh = 32 * w + 16 * p + lrow;
            #pragma unroll
            for (int r = 0; r < 4; r++) {
                int row = m * 16 + lr4 + r;
                if (r0 + row < nrows) {
                    size_t o = (size_t)(r0 + row) * HDIM + hh;
                    float gi = acc[m][0][p][r], gf = acc[m][1][p][r];
                    float gg = acc[m][2][p][r], go = acc[m][3][p][r];
                    float cn = sigmf(gf) * cbuf[o] + sigmf(gi) * tanhf(gg);
                    float hn = sigmf(go) * tanhf(cn);
                    cbuf[o] = cn;
                    ushort hb = f2bf(hn);
                    ushort lb = f2bf(hn - bf2f(hb));
                    Hhi[o] = hb;
                    Hlo[o] = lb;
                    if (LAST) {
                        outh[o] = hn;
                        outc[o] = cn;
                        AsH[row][128 + hh] = hb;
                        AsL[row][128 + hh] = lb;
                    }
                }
            }
        }
    }

    if (LAST) {
        __syncthreads();   // h_T ready in LDS
        f32x4 hacc[2];
        {
            float b = bout[w * 16 + lrow];
            hacc[0] = (f32x4){b, b, b, b};
            hacc[1] = hacc[0];
        }
        #pragma unroll
        for (int kt = 0; kt < 4; kt++) {
            s8 aH[2], aL[2];
            #pragma unroll
            for (int m = 0; m < 2; m++) {
                int row = m * 16 + lrow;
                aH[m] = *(const s8*)&AsH[row][128 + kt * 32 + lk];
                aL[m] = *(const s8*)&AsL[row][128 + kt * 32 + lk];
            }
            uint4 bh4 = Whi[(kt * 4 + w) * 64 + l];
            uint4 bl4 = Wlo[(kt * 4 + w) * 64 + l];
            s8 bh = __builtin_bit_cast(s8, bh4);
            s8 bl = __builtin_bit_cast(s8, bl4);
            #pragma unroll
            for (int m = 0; m < 2; m++) {
                hacc[m] = __builtin_amdgcn_mfma_f32_16x16x32_bf16(aH[m], bh, hacc[m], 0, 0, 0);
                hacc[m] = __builtin_amdgcn_mfma_f32_16x16x32_bf16(aH[m], bl, hacc[m], 0, 0, 0);
                hacc[m] = __builtin_amdgcn_mfma_f32_16x16x32_bf16(aL[m], bh, hacc[m], 0, 0, 0);
            }
        }
        #pragma unroll
        for (int m = 0; m < 2; m++) {
            #pragma unroll
            for (int r = 0; r < 4; r++) {
                int row = r0 + m * 16 + lr4 + r;
                if (row < nrows)
                    outp[(size_t)row * ODIM + w * 16 + lrow] = hacc[m][r];
            }
        }
    }
}

// ---------------- launch ----------------

static inline int cdiv(long long a, long long b) { return (int)((a + b - 1) / b); }

extern "C" void kernel_launch(void* const* d_in, const int* in_sizes, int n_in,
                              void* d_out, int out_size, void* d_ws, size_t ws_size,
                              hipStream_t stream) {
    const float* x_seq = (const float*)d_in[0];
    const int*   edges = (const int*)d_in[1];
    const float* W1    = (const float*)d_in[2];
    const float* b1    = (const float*)d_in[3];
    const float* W2    = (const float*)d_in[4];
    const float* b2    = (const float*)d_in[5];
    const float* Wih   = (const float*)d_in[6];
    const float* Whh   = (const float*)d_in[7];
    const float* bih   = (const float*)d_in[8];
    const float* bhh   = (const float*)d_in[9];
    const float* Wout  = (const float*)d_in[10];
    const float* bout  = (const float*)d_in[11];
    float* out = (float*)d_out;

    const int N = in_sizes[0] / (TSTEPS * FDIM);   // 50000
    const int E = in_sizes[1] / (2 * TSTEPS);      // 600000
    const int NT8 = TSTEPS * N;                    // 400000
    const size_t NP = ((size_t)NT8 + 255) & ~(size_t)255;
    const int NCHUNKS = cdiv(NT8, SCAN_CHUNK);
    const size_t nf = (size_t)N * FDIM;

    // workspace layout
    float* ws = (float*)d_ws;
    float* dinv = ws;                              // NP f32
    float* wcat = dinv + NP;                       // 256*512
    float* bsum = wcat + 131072;                   // 512
    uint* pW1hi = (uint*)(bsum + 512);             // 8192 each
    uint* pW1lo = pW1hi + 8192;
    uint* pW2hi = pW1lo + 8192;
    uint* pW2lo = pW2hi + 8192;
    uint* pWchi = pW2lo + 8192;                    // 65536 each
    uint* pWclo = pWchi + 65536;
    uint* pWohi = pWclo + 65536;                   // 4096 each
    uint* pWolo = pWohi + 4096;
    float* cbuf = (float*)(pWolo + 4096);          // [N][128] f32
    ushort* hhi = (ushort*)(cbuf + nf);            // [N][128] bf16 each
    ushort* hlo = hhi + nf;
    ushort* xwhi = hlo + nf;                       // [8N][128] each
    ushort* xwlo = xwhi + (size_t)NT8 * 128;
    ushort* h1hi = xwlo + (size_t)NT8 * 128;
    ushort* h1lo = h1hi + (size_t)NT8 * 128;
    ushort* ehi  = h1lo + (size_t)NT8 * 128;
    ushort* elo  = ehi  + (size_t)NT8 * 128;
    int* deg       = (int*)(elo + (size_t)NT8 * 128);
    int* row_start = deg + NP;
    int* cursor    = row_start + NP;
    int* partial   = cursor + NP;                  // 512
    int* csr_src   = partial + 512;                // 8E

    // weights prep
    prep_lstm_w<<<cdiv(256 * GDIM, 256), 256, 0, stream>>>(Wih, Whh, bih, bhh, wcat, bsum);
    pack_b<<<32, 256, 0, stream>>>(W1, 128, 128, pW1hi, pW1lo);
    pack_b<<<32, 256, 0, stream>>>(W2, 128, 128, pW2hi, pW2lo);
    pack_b<<<256, 256, 0, stream>>>(wcat, 256, GDIM, pWchi, pWclo);
    pack_b<<<16, 256, 0, stream>>>(Wout, 128, ODIM, pWohi, pWolo);

    // zero c (f32) and h split (bf16 hi/lo): contiguous region of nf + nf/2 + nf/2 floats... 
    // cbuf nf floats, hhi+hlo = nf ushorts *2 = nf floats -> 2*nf ints total
    zero_int<<<cdiv(2 * (long long)nf, 256), 256, 0, stream>>>((int*)cbuf, (int)(2 * nf));

    // batched CSR build (all 8 timesteps as one disjoint graph)
    zero_int<<<cdiv(NP, 256), 256, 0, stream>>>(deg, (int)NP);
    deg_count8<<<cdiv((long long)TSTEPS * E, 256), 256, 0, stream>>>(edges, deg, E, N);
    scan_partial<<<NCHUNKS, 256, 0, stream>>>(deg, partial, NT8);
    scan_offsets1<<<1, 512, 0, stream>>>(partial, row_start, NCHUNKS, NT8);
    scan_final<<<NCHUNKS, 256, 0, stream>>>(deg, partial, row_start, cursor, NT8);
    deg_to_dinv<<<cdiv(NT8, 256), 256, 0, stream>>>(deg, dinv, NT8);
    edge_scatter8<<<cdiv((long long)TSTEPS * E, 256), 256, 0, stream>>>(edges, cursor, csr_src, E, N);

    // layer 1 (batched over all t)
    gemm_mfma128<false><<<cdiv(NT8, 64), 256, 0, stream>>>(
        x_seq, nullptr, nullptr, (const uint4*)pW1hi, (const uint4*)pW1lo, xwhi, xwlo, NT8);
    agg_gather8<<<cdiv((long long)NT8 * 64, 256), 256, 0, stream>>>(
        row_start, csr_src, (const uint*)xwhi, (const uint*)xwlo, dinv, b1,
        (uint*)h1hi, (uint*)h1lo, NT8);

    // layer 2 (batched)
    gemm_mfma128<true><<<cdiv(NT8, 64), 256, 0, stream>>>(
        nullptr, h1hi, h1lo, (const uint4*)pW2hi, (const uint4*)pW2lo, xwhi, xwlo, NT8);
    agg_gather8<<<cdiv((long long)NT8 * 64, 256), 256, 0, stream>>>(
        row_start, csr_src, (const uint*)xwhi, (const uint*)xwlo, dinv, b2,
        (uint*)ehi, (uint*)elo, NT8);

    // LSTM per timestep; last one fuses head + h/c outputs
    float* out_h = out + (size_t)N * ODIM;
    float* out_c = out_h + (size_t)N * HDIM;
    for (int t = 0; t < TSTEPS - 1; t++) {
        lstm_step_t<false><<<cdiv(N, 32), 256, 0, stream>>>(
            ehi + (size_t)t * N * 128, elo + (size_t)t * N * 128,
            hhi, hlo, (const uint4*)pWchi, (const uint4*)pWclo, bsum, cbuf,
            nullptr, nullptr, nullptr, nullptr, nullptr, nullptr, N);
    }
    lstm_step_t<true><<<cdiv(N, 32), 256, 0, stream>>>(
        ehi + (size_t)(TSTEPS - 1) * N * 128, elo + (size_t)(TSTEPS - 1) * N * 128,
        hhi, hlo, (const uint4*)pWchi, (const uint4*)pWclo, bsum, cbuf,
        (const uint4*)pWohi, (const uint4*)pWolo, bout,
        out, out_h, out_c, N);
}

// Round 7
// 1695.090 us; speedup vs baseline: 12.8708x; 1.2391x over previous
//
#include <hip/hip_runtime.h>
#include <math.h>

#define TSTEPS 8
#define FDIM 128
#define HDIM 128
#define ODIM 64
#define GDIM 512
#define BUCKR 2048
#define BUCKR_SHIFT 11
#define BPT 32   // blocks per timestep in bin_count / bin_scatter

typedef __attribute__((ext_vector_type(4))) float f32x4;
typedef __attribute__((ext_vector_type(8))) short s8;

__device__ __forceinline__ float sigmf(float x) { return 1.0f / (1.0f + __expf(-x)); }

__device__ __forceinline__ ushort f2bf(float x) {
    uint u = __float_as_uint(x);
    u += 0x7FFFu + ((u >> 16) & 1u);
    return (ushort)(u >> 16);
}
__device__ __forceinline__ float bf2f(ushort h) { return __uint_as_float(((uint)h) << 16); }

// ---------------- setup kernels ----------------

__global__ void prep_lstm_w(const float* __restrict__ wih, const float* __restrict__ whh,
                            const float* __restrict__ bih, const float* __restrict__ bhh,
                            float* __restrict__ wcat, float* __restrict__ bsum) {
    int idx = blockIdx.x * 256 + threadIdx.x;
    if (idx < 256 * GDIM) {
        int k = idx >> 9;
        int col = idx & 511;
        float v = (k < HDIM) ? wih[col * HDIM + k] : whh[col * HDIM + (k - HDIM)];
        wcat[idx] = v;
        if (k == 0) bsum[col] = bih[col] + bhh[col];
    }
}

// pack B [K][NC] f32 (k-major) into MFMA-frag order, split hi/lo bf16.
__global__ void pack_b(const float* __restrict__ B, int K, int NC,
                       uint* __restrict__ hi, uint* __restrict__ lo) {
    int total = (K / 32) * (NC / 16) * 256;
    int idx = blockIdx.x * 256 + threadIdx.x;
    if (idx >= total) return;
    int d = idx & 3, l = (idx >> 2) & 63, t = idx >> 8;
    int NT = NC / 16;
    int kt = t / NT, nt = t % NT;
    int k = kt * 32 + (l >> 4) * 8 + d * 2;
    int col = nt * 16 + (l & 15);
    float va = B[(size_t)k * NC + col];
    float vb = B[(size_t)(k + 1) * NC + col];
    ushort ha = f2bf(va), hb = f2bf(vb);
    float ra = va - bf2f(ha), rb = vb - bf2f(hb);
    hi[idx] = (uint)ha | ((uint)hb << 16);
    lo[idx] = (uint)f2bf(ra) | ((uint)f2bf(rb) << 16);
}

__global__ void zero_int(int* __restrict__ p, int n) {
    int idx = blockIdx.x * 256 + threadIdx.x;
    if (idx < n) p[idx] = 0;
}

// ---------------- bucketed CSR build ----------------
// buckets of BUCKR consecutive global node ids (gid = t*N + dst)

__global__ __launch_bounds__(256) void bin_count(const int* __restrict__ edges,
                                                 int* __restrict__ gcount,
                                                 int E, int N, int nbuck) {
    __shared__ int h[1024];
    int tid = threadIdx.x;
    int t = blockIdx.x >> 5, b = blockIdx.x & 31;
    int ce = (E + BPT - 1) / BPT;
    int e0 = b * ce, e1 = min(e0 + ce, E);
    for (int i = tid; i < 1024; i += 256) h[i] = 0;
    __syncthreads();
    const int* dstp = edges + (size_t)t * 2 * E + E;
    for (int i = e0 + tid; i < e1; i += 256) {
        int gid = t * N + dstp[i];
        atomicAdd(&h[gid >> BUCKR_SHIFT], 1);
    }
    __syncthreads();
    for (int i = tid; i < nbuck; i += 256) {
        int c = h[i];
        if (c) atomicAdd(&gcount[i], c);
    }
}

__global__ __launch_bounds__(1024) void scan_buckets(const int* __restrict__ gcount,
                                                     int* __restrict__ bucket_start,
                                                     int* __restrict__ bucket_cursor,
                                                     int nbuck, int* __restrict__ row_start,
                                                     int nTotal, int totalE) {
    __shared__ int s[1024];
    int t = threadIdx.x;
    int own = (t < nbuck) ? gcount[t] : 0;
    s[t] = own; __syncthreads();
    for (int off = 1; off < 1024; off <<= 1) {
        int add = (t >= off) ? s[t - off] : 0;
        __syncthreads();
        s[t] += add;
        __syncthreads();
    }
    if (t < nbuck) {
        int excl = s[t] - own;
        bucket_start[t] = excl;
        bucket_cursor[t] = excl;
    }
    if (t == 0) {
        bucket_start[nbuck] = totalE;
        row_start[nTotal] = totalE;
    }
}

__global__ __launch_bounds__(256) void bin_scatter(const int* __restrict__ edges,
                                                   int* __restrict__ bucket_cursor,
                                                   uint2* __restrict__ staged,
                                                   int E, int N, int nbuck) {
    __shared__ int h[1024];
    __shared__ int base[1024];
    int tid = threadIdx.x;
    int t = blockIdx.x >> 5, b = blockIdx.x & 31;
    int ce = (E + BPT - 1) / BPT;
    int e0 = b * ce, e1 = min(e0 + ce, E);
    for (int i = tid; i < 1024; i += 256) h[i] = 0;
    __syncthreads();
    const int* srcp = edges + (size_t)t * 2 * E;
    const int* dstp = srcp + E;
    for (int i = e0 + tid; i < e1; i += 256) {
        int gid = t * N + dstp[i];
        atomicAdd(&h[gid >> BUCKR_SHIFT], 1);
    }
    __syncthreads();
    for (int i = tid; i < nbuck; i += 256) {
        int c = h[i];
        if (c) base[i] = atomicAdd(&bucket_cursor[i], c);
        h[i] = 0;
    }
    __syncthreads();
    for (int i = e0 + tid; i < e1; i += 256) {
        int sgid = t * N + srcp[i];
        int dgid = t * N + dstp[i];
        int bk = dgid >> BUCKR_SHIFT;
        int loc = atomicAdd(&h[bk], 1);
        staged[base[bk] + loc] = make_uint2((uint)sgid, (uint)dgid);
    }
}

// one block per bucket: local deg count, local scan, write row_start/dinv, scatter srcs
__global__ __launch_bounds__(256) void bin_csr(const uint2* __restrict__ staged,
                                               const int* __restrict__ bucket_start,
                                               int* __restrict__ row_start,
                                               int* __restrict__ csr_src,
                                               float* __restrict__ dinv, int nTotal) {
    __shared__ int cnt[BUCKR];
    __shared__ int part[256];
    int tid = threadIdx.x;
    int node0 = blockIdx.x << BUCKR_SHIFT;
    int nloc = min(BUCKR, nTotal - node0);
    int ebase = bucket_start[blockIdx.x], eend = bucket_start[blockIdx.x + 1];

    for (int j = tid; j < BUCKR; j += 256) cnt[j] = 0;
    __syncthreads();
    for (int e = ebase + tid; e < eend; e += 256)
        atomicAdd(&cnt[(int)staged[e].y - node0], 1);
    __syncthreads();

    int s = 0;
    #pragma unroll
    for (int k = 0; k < 8; k++) s += cnt[tid * 8 + k];
    part[tid] = s; __syncthreads();
    for (int off = 1; off < 256; off <<= 1) {
        int add = (tid >= off) ? part[tid - off] : 0;
        __syncthreads();
        part[tid] += add;
        __syncthreads();
    }
    int run = part[tid] - s;   // exclusive prefix of this thread's slice
    #pragma unroll
    for (int k = 0; k < 8; k++) {
        int j = tid * 8 + k;
        int c = cnt[j];
        if (j < nloc) {
            row_start[node0 + j] = ebase + run;
            dinv[node0 + j] = rsqrtf((float)(c + 1));
        }
        cnt[j] = run;   // becomes the local cursor
        run += c;
    }
    __syncthreads();
    for (int e = ebase + tid; e < eend; e += 256) {
        uint2 ed = staged[e];
        int d = (int)ed.y - node0;
        int pos = ebase + atomicAdd(&cnt[d], 1);
        csr_src[pos] = (int)ed.x;
    }
}

// ---------------- gather aggregation over all 8N rows ----------------

__global__ __launch_bounds__(256) void agg_gather8(
    const int* __restrict__ row_start, const int* __restrict__ csr_src,
    const uint* __restrict__ xh, const uint* __restrict__ xl,
    const float* __restrict__ dinv, const float* __restrict__ bias,
    uint* __restrict__ ohi, uint* __restrict__ olo, int nTotal)
{
    int w = (blockIdx.x * 256 + threadIdx.x) >> 6;
    int lane = threadIdx.x & 63;
    if (w >= nTotal) return;
    float dr = dinv[w];
    float cc = dr * dr;
    uint shv = xh[(size_t)w * 64 + lane];
    uint slv = xl[(size_t)w * 64 + lane];
    float a0 = (__uint_as_float(shv << 16) + __uint_as_float(slv << 16)) * cc;
    float a1 = (__uint_as_float(shv & 0xFFFF0000u) + __uint_as_float(slv & 0xFFFF0000u)) * cc;
    int e = row_start[w], e1 = row_start[w + 1];
    for (; e + 4 <= e1; e += 4) {
        int s0 = csr_src[e], s1 = csr_src[e + 1], s2 = csr_src[e + 2], s3 = csr_src[e + 3];
        float c0 = dinv[s0] * dr, c1 = dinv[s1] * dr, c2 = dinv[s2] * dr, c3 = dinv[s3] * dr;
        uint u0 = xh[(size_t)s0 * 64 + lane];
        uint u1 = xh[(size_t)s1 * 64 + lane];
        uint u2 = xh[(size_t)s2 * 64 + lane];
        uint u3 = xh[(size_t)s3 * 64 + lane];
        a0 = fmaf(__uint_as_float(u0 << 16), c0, a0);
        a1 = fmaf(__uint_as_float(u0 & 0xFFFF0000u), c0, a1);
        a0 = fmaf(__uint_as_float(u1 << 16), c1, a0);
        a1 = fmaf(__uint_as_float(u1 & 0xFFFF0000u), c1, a1);
        a0 = fmaf(__uint_as_float(u2 << 16), c2, a0);
        a1 = fmaf(__uint_as_float(u2 & 0xFFFF0000u), c2, a1);
        a0 = fmaf(__uint_as_float(u3 << 16), c3, a0);
        a1 = fmaf(__uint_as_float(u3 & 0xFFFF0000u), c3, a1);
    }
    for (; e < e1; e++) {
        int s = csr_src[e];
        float cf = dinv[s] * dr;
        uint u = xh[(size_t)s * 64 + lane];
        a0 = fmaf(__uint_as_float(u << 16), cf, a0);
        a1 = fmaf(__uint_as_float(u & 0xFFFF0000u), cf, a1);
    }
    float2 b = ((const float2*)bias)[lane];
    a0 = fmaxf(a0 + b.x, 0.f);
    a1 = fmaxf(a1 + b.y, 0.f);
    ushort h0 = f2bf(a0), h1 = f2bf(a1);
    ohi[(size_t)w * 64 + lane] = (uint)h0 | ((uint)h1 << 16);
    olo[(size_t)w * 64 + lane] = (uint)f2bf(a0 - bf2f(h0)) | ((uint)f2bf(a1 - bf2f(h1)) << 16);
}

// ---------------- MFMA GEMM: [M,128] @ [128,128] -> split bf16 out ----------------

template<bool SPLITSRC>
__global__ __launch_bounds__(256) void gemm_mfma128(
    const float* __restrict__ A32, const ushort* __restrict__ Ahi, const ushort* __restrict__ Alo,
    const uint4* __restrict__ Bhi, const uint4* __restrict__ Blo,
    ushort* __restrict__ Chi, ushort* __restrict__ Clo, int nrows)
{
    __shared__ ushort AsH[64][136];
    __shared__ ushort AsL[64][136];
    const int r0 = blockIdx.x * 64;
    const int tid = threadIdx.x;

    if (SPLITSRC) {
        for (int v = tid; v < 64 * 16; v += 256) {
            int row = v >> 4, seg = v & 15;
            uint4 h = make_uint4(0, 0, 0, 0), L = make_uint4(0, 0, 0, 0);
            if (r0 + row < nrows) {
                h = *(const uint4*)(Ahi + (size_t)(r0 + row) * 128 + seg * 8);
                L = *(const uint4*)(Alo + (size_t)(r0 + row) * 128 + seg * 8);
            }
            *(uint4*)&AsH[row][seg * 8] = h;
            *(uint4*)&AsL[row][seg * 8] = L;
        }
    } else {
        for (int v = tid; v < 64 * 16; v += 256) {
            int row = v >> 4, seg = v & 15;
            float4 a = make_float4(0.f, 0.f, 0.f, 0.f), b = a;
            if (r0 + row < nrows) {
                const float4* src = (const float4*)A32 + (size_t)(r0 + row) * 32 + seg * 2;
                a = src[0]; b = src[1];
            }
            float vv[8] = {a.x, a.y, a.z, a.w, b.x, b.y, b.z, b.w};
            uint hh[4], ll[4];
            #pragma unroll
            for (int i = 0; i < 4; i++) {
                float v0 = vv[2 * i], v1 = vv[2 * i + 1];
                ushort h0 = f2bf(v0), h1 = f2bf(v1);
                hh[i] = (uint)h0 | ((uint)h1 << 16);
                ll[i] = (uint)f2bf(v0 - bf2f(h0)) | ((uint)f2bf(v1 - bf2f(h1)) << 16);
            }
            *(uint4*)&AsH[row][seg * 8] = make_uint4(hh[0], hh[1], hh[2], hh[3]);
            *(uint4*)&AsL[row][seg * 8] = make_uint4(ll[0], ll[1], ll[2], ll[3]);
        }
    }
    __syncthreads();

    const int l = tid & 63, w = tid >> 6;
    const int wm = w & 1, wn = w >> 1;
    const int lrow = l & 15, lk = (l >> 4) * 8;

    f32x4 acc[2][4];
    #pragma unroll
    for (int m = 0; m < 2; m++)
        #pragma unroll
        for (int p = 0; p < 4; p++) acc[m][p] = (f32x4){0.f, 0.f, 0.f, 0.f};

    for (int kt = 0; kt < 4; kt++) {
        s8 aH[2], aL[2];
        #pragma unroll
        for (int m = 0; m < 2; m++) {
            int row = (2 * wm + m) * 16 + lrow;
            aH[m] = *(const s8*)&AsH[row][kt * 32 + lk];
            aL[m] = *(const s8*)&AsL[row][kt * 32 + lk];
        }
        #pragma unroll
        for (int p = 0; p < 4; p++) {
            int nt = 4 * wn + p;
            uint4 bh4 = Bhi[(kt * 8 + nt) * 64 + l];
            uint4 bl4 = Blo[(kt * 8 + nt) * 64 + l];
            s8 bh = __builtin_bit_cast(s8, bh4);
            s8 bl = __builtin_bit_cast(s8, bl4);
            #pragma unroll
            for (int m = 0; m < 2; m++) {
                acc[m][p] = __builtin_amdgcn_mfma_f32_16x16x32_bf16(aH[m], bh, acc[m][p], 0, 0, 0);
                acc[m][p] = __builtin_amdgcn_mfma_f32_16x16x32_bf16(aH[m], bl, acc[m][p], 0, 0, 0);
                acc[m][p] = __builtin_amdgcn_mfma_f32_16x16x32_bf16(aL[m], bh, acc[m][p], 0, 0, 0);
            }
        }
    }

    const int lr4 = (l >> 4) * 4;
    #pragma unroll
    for (int m = 0; m < 2; m++) {
        #pragma unroll
        for (int p = 0; p < 4; p++) {
            int col = (4 * wn + p) * 16 + lrow;
            #pragma unroll
            for (int r = 0; r < 4; r++) {
                int row = r0 + (2 * wm + m) * 16 + lr4 + r;
                if (row < nrows) {
                    float v = acc[m][p][r];
                    ushort h = f2bf(v);
                    Chi[(size_t)row * 128 + col] = h;
                    Clo[(size_t)row * 128 + col] = f2bf(v - bf2f(h));
                }
            }
        }
    }
}

// ---------------- per-timestep LSTM; LAST fuses head + outputs ----------------

template<bool LAST>
__global__ __launch_bounds__(256) void lstm_step_t(
    const ushort* __restrict__ Ehi, const ushort* __restrict__ Elo,
    ushort* __restrict__ Hhi, ushort* __restrict__ Hlo,
    const uint4* __restrict__ Bhi, const uint4* __restrict__ Blo,
    const float* __restrict__ bsum, float* __restrict__ cbuf,
    const uint4* __restrict__ Whi, const uint4* __restrict__ Wlo,
    const float* __restrict__ bout,
    float* __restrict__ outp, float* __restrict__ outh, float* __restrict__ outc,
    int nrows)
{
    __shared__ ushort AsH[32][264];
    __shared__ ushort AsL[32][264];
    const int r0 = blockIdx.x * 32;
    const int tid = threadIdx.x;
    const int l = tid & 63, w = tid >> 6;
    const int lrow = l & 15, lk = (l >> 4) * 8, lr4 = (l >> 4) * 4;

    for (int v = tid; v < 32 * 32; v += 256) {
        int row = v >> 5, seg = v & 31;
        uint4 h = make_uint4(0, 0, 0, 0), L = make_uint4(0, 0, 0, 0);
        if (r0 + row < nrows) {
            if (seg < 16) {
                size_t g = (size_t)(r0 + row) * 128 + seg * 8;
                h = *(const uint4*)(Ehi + g);
                L = *(const uint4*)(Elo + g);
            } else {
                size_t g = (size_t)(r0 + row) * 128 + (seg - 16) * 8;
                h = *(const uint4*)(Hhi + g);
                L = *(const uint4*)(Hlo + g);
            }
        }
        *(uint4*)&AsH[row][seg * 8] = h;
        *(uint4*)&AsL[row][seg * 8] = L;
    }
    __syncthreads();

    f32x4 acc[2][4][2];
    #pragma unroll
    for (int m = 0; m < 2; m++)
        #pragma unroll
        for (int q = 0; q < 4; q++)
            #pragma unroll
            for (int p = 0; p < 2; p++) {
                float b = bsum[q * 128 + 32 * w + 16 * p + lrow];
                acc[m][q][p] = (f32x4){b, b, b, b};
            }

    #pragma unroll
    for (int kt = 0; kt < 8; kt++) {
        s8 aH[2], aL[2];
        #pragma unroll
        for (int m = 0; m < 2; m++) {
            int row = m * 16 + lrow;
            aH[m] = *(const s8*)&AsH[row][kt * 32 + lk];
            aL[m] = *(const s8*)&AsL[row][kt * 32 + lk];
        }
        #pragma unroll
        for (int q = 0; q < 4; q++) {
            #pragma unroll
            for (int p = 0; p < 2; p++) {
                int nt = 8 * q + 2 * w + p;
                uint4 bh4 = Bhi[((size_t)kt * 32 + nt) * 64 + l];
                uint4 bl4 = Blo[((size_t)kt * 32 + nt) * 64 + l];
                s8 bh = __builtin_bit_cast(s8, bh4);
                s8 bl = __builtin_bit_cast(s8, bl4);
                #pragma unroll
                for (int m = 0; m < 2; m++) {
                    acc[m][q][p] = __builtin_amdgcn_mfma_f32_16x16x32_bf16(aH[m], bh, acc[m][q][p], 0, 0, 0);
                    acc[m][q][p] = __builtin_amdgcn_mfma_f32_16x16x32_bf16(aH[m], bl, acc[m][q][p], 0, 0, 0);
                    acc[m][q][p] = __builtin_amdgcn_mfma_f32_16x16x32_bf16(aL[m], bh, acc[m][q][p], 0, 0, 0);
                }
            }
        }
    }
    if (LAST) __syncthreads();

    #pragma unroll
    for (int m = 0; m < 2; m++) {
        #pragma unroll
        for (int p = 0; p < 2; p++) {
            int hh = 32 * w + 16 * p + lrow;
            #pragma unroll
            for (int r = 0; r < 4; r++) {
                int row = m * 16 + lr4 + r;
                if (r0 + row < nrows) {
                    size_t o = (size_t)(r0 + row) * HDIM + hh;
                    float gi = acc[m][0][p][r], gf = acc[m][1][p][r];
                    float gg = acc[m][2][p][r], go = acc[m][3][p][r];
                    float cn = sigmf(gf) * cbuf[o] + sigmf(gi) * tanhf(gg);
                    float hn = sigmf(go) * tanhf(cn);
                    cbuf[o] = cn;
                    ushort hb = f2bf(hn);
                    ushort lb = f2bf(hn - bf2f(hb));
                    Hhi[o] = hb;
                    Hlo[o] = lb;
                    if (LAST) {
                        outh[o] = hn;
                        outc[o] = cn;
                        AsH[row][128 + hh] = hb;
                        AsL[row][128 + hh] = lb;
                    }
                }
            }
        }
    }

    if (LAST) {
        __syncthreads();
        f32x4 hacc[2];
        {
            float b = bout[w * 16 + lrow];
            hacc[0] = (f32x4){b, b, b, b};
            hacc[1] = hacc[0];
        }
        #pragma unroll
        for (int kt = 0; kt < 4; kt++) {
            s8 aH[2], aL[2];
            #pragma unroll
            for (int m = 0; m < 2; m++) {
                int row = m * 16 + lrow;
                aH[m] = *(const s8*)&AsH[row][128 + kt * 32 + lk];
                aL[m] = *(const s8*)&AsL[row][128 + kt * 32 + lk];
            }
            uint4 bh4 = Whi[(kt * 4 + w) * 64 + l];
            uint4 bl4 = Wlo[(kt * 4 + w) * 64 + l];
            s8 bh = __builtin_bit_cast(s8, bh4);
            s8 bl = __builtin_bit_cast(s8, bl4);
            #pragma unroll
            for (int m = 0; m < 2; m++) {
                hacc[m] = __builtin_amdgcn_mfma_f32_16x16x32_bf16(aH[m], bh, hacc[m], 0, 0, 0);
                hacc[m] = __builtin_amdgcn_mfma_f32_16x16x32_bf16(aH[m], bl, hacc[m], 0, 0, 0);
                hacc[m] = __builtin_amdgcn_mfma_f32_16x16x32_bf16(aL[m], bh, hacc[m], 0, 0, 0);
            }
        }
        #pragma unroll
        for (int m = 0; m < 2; m++) {
            #pragma unroll
            for (int r = 0; r < 4; r++) {
                int row = r0 + m * 16 + lr4 + r;
                if (row < nrows)
                    outp[(size_t)row * ODIM + w * 16 + lrow] = hacc[m][r];
            }
        }
    }
}

// ---------------- launch ----------------

static inline int cdiv(long long a, long long b) { return (int)((a + b - 1) / b); }

extern "C" void kernel_launch(void* const* d_in, const int* in_sizes, int n_in,
                              void* d_out, int out_size, void* d_ws, size_t ws_size,
                              hipStream_t stream) {
    const float* x_seq = (const float*)d_in[0];
    const int*   edges = (const int*)d_in[1];
    const float* W1    = (const float*)d_in[2];
    const float* b1    = (const float*)d_in[3];
    const float* W2    = (const float*)d_in[4];
    const float* b2    = (const float*)d_in[5];
    const float* Wih   = (const float*)d_in[6];
    const float* Whh   = (const float*)d_in[7];
    const float* bih   = (const float*)d_in[8];
    const float* bhh   = (const float*)d_in[9];
    const float* Wout  = (const float*)d_in[10];
    const float* bout  = (const float*)d_in[11];
    float* out = (float*)d_out;

    const int N = in_sizes[0] / (TSTEPS * FDIM);   // 50000
    const int E = in_sizes[1] / (2 * TSTEPS);      // 600000
    const int NT8 = TSTEPS * N;                    // 400000
    const size_t NP = ((size_t)NT8 + 255) & ~(size_t)255;
    const int NBUCK = cdiv(NT8, BUCKR);            // 196
    const size_t nf = (size_t)N * FDIM;
    const int E8 = TSTEPS * E;

    // workspace layout
    float* ws = (float*)d_ws;
    float* dinv = ws;                              // NP f32
    float* wcat = dinv + NP;                       // 256*512
    float* bsum = wcat + 131072;                   // 512
    uint* pW1hi = (uint*)(bsum + 512);             // 8192 each
    uint* pW1lo = pW1hi + 8192;
    uint* pW2hi = pW1lo + 8192;
    uint* pW2lo = pW2hi + 8192;
    uint* pWchi = pW2lo + 8192;                    // 65536 each
    uint* pWclo = pWchi + 65536;
    uint* pWohi = pWclo + 65536;                   // 4096 each
    uint* pWolo = pWohi + 4096;
    float* cbuf = (float*)(pWolo + 4096);          // [N][128] f32
    ushort* hhi = (ushort*)(cbuf + nf);            // [N][128] bf16 each
    ushort* hlo = hhi + nf;
    ushort* xwhi = hlo + nf;                       // [8N][128] each
    ushort* xwlo = xwhi + (size_t)NT8 * 128;
    ushort* h1hi = xwlo + (size_t)NT8 * 128;
    ushort* h1lo = h1hi + (size_t)NT8 * 128;
    ushort* ehi  = h1lo + (size_t)NT8 * 128;
    ushort* elo  = ehi  + (size_t)NT8 * 128;
    uint2* staged  = (uint2*)(elo + (size_t)NT8 * 128);   // 8E uint2 (8B aligned)
    int* csr_src   = (int*)(staged + E8);                 // 8E
    int* row_start = csr_src + E8;                        // NT8+1 (pad to NP+2)
    int* gcount    = row_start + NP + 2;                  // 1024
    int* bucket_start  = gcount + 1024;                   // 1026
    int* bucket_cursor = bucket_start + 1026;             // 1024

    // weights prep
    prep_lstm_w<<<cdiv(256 * GDIM, 256), 256, 0, stream>>>(Wih, Whh, bih, bhh, wcat, bsum);
    pack_b<<<32, 256, 0, stream>>>(W1, 128, 128, pW1hi, pW1lo);
    pack_b<<<32, 256, 0, stream>>>(W2, 128, 128, pW2hi, pW2lo);
    pack_b<<<256, 256, 0, stream>>>(wcat, 256, GDIM, pWchi, pWclo);
    pack_b<<<16, 256, 0, stream>>>(Wout, 128, ODIM, pWohi, pWolo);

    // zero c (f32) + h split (bf16 hi/lo): contiguous 2*nf ints
    zero_int<<<cdiv(2 * (long long)nf, 256), 256, 0, stream>>>((int*)cbuf, (int)(2 * nf));

    // bucketed CSR build
    zero_int<<<4, 256, 0, stream>>>(gcount, 1024);
    bin_count<<<TSTEPS * BPT, 256, 0, stream>>>(edges, gcount, E, N, NBUCK);
    scan_buckets<<<1, 1024, 0, stream>>>(gcount, bucket_start, bucket_cursor, NBUCK,
                                         row_start, NT8, E8);
    bin_scatter<<<TSTEPS * BPT, 256, 0, stream>>>(edges, bucket_cursor, staged, E, N, NBUCK);
    bin_csr<<<NBUCK, 256, 0, stream>>>(staged, bucket_start, row_start, csr_src, dinv, NT8);

    // layer 1 (batched over all t)
    gemm_mfma128<false><<<cdiv(NT8, 64), 256, 0, stream>>>(
        x_seq, nullptr, nullptr, (const uint4*)pW1hi, (const uint4*)pW1lo, xwhi, xwlo, NT8);
    agg_gather8<<<cdiv((long long)NT8 * 64, 256), 256, 0, stream>>>(
        row_start, csr_src, (const uint*)xwhi, (const uint*)xwlo, dinv, b1,
        (uint*)h1hi, (uint*)h1lo, NT8);

    // layer 2 (batched)
    gemm_mfma128<true><<<cdiv(NT8, 64), 256, 0, stream>>>(
        nullptr, h1hi, h1lo, (const uint4*)pW2hi, (const uint4*)pW2lo, xwhi, xwlo, NT8);
    agg_gather8<<<cdiv((long long)NT8 * 64, 256), 256, 0, stream>>>(
        row_start, csr_src, (const uint*)xwhi, (const uint*)xwlo, dinv, b2,
        (uint*)ehi, (uint*)elo, NT8);

    // LSTM per timestep; last fuses head + h/c outputs
    float* out_h = out + (size_t)N * ODIM;
    float* out_c = out_h + (size_t)N * HDIM;
    for (int t = 0; t < TSTEPS - 1; t++) {
        lstm_step_t<false><<<cdiv(N, 32), 256, 0, stream>>>(
            ehi + (size_t)t * N * 128, elo + (size_t)t * N * 128,
            hhi, hlo, (const uint4*)pWchi, (const uint4*)pWclo, bsum, cbuf,
            nullptr, nullptr, nullptr, nullptr, nullptr, nullptr, N);
    }
    lstm_step_t<true><<<cdiv(N, 32), 256, 0, stream>>>(
        ehi + (size_t)(TSTEPS - 1) * N * 128, elo + (size_t)(TSTEPS - 1) * N * 128,
        hhi, hlo, (const uint4*)pWchi, (const uint4*)pWclo, bsum, cbuf,
        (const uint4*)pWohi, (const uint4*)pWolo, bout,
        out, out_h, out_c, N);
}